// Round 1
// baseline (1400.791 us; speedup 1.0000x reference)
//
#include <hip/hip_runtime.h>

#define N_NODES 100000
#define N_EDGES 400000
#define N_GRAPHS 2000
#define NODE_F 78
#define HID 128

// ---------------- degree / dinv ----------------

__global__ void init_ones_k(float* __restrict__ p, int n) {
    int i = blockIdx.x * blockDim.x + threadIdx.x;
    if (i < n) p[i] = 1.0f;  // self-loop contributes 1 to every degree
}

__global__ void count_deg_k(const int* __restrict__ dst, float* __restrict__ deg) {
    int e = blockIdx.x * blockDim.x + threadIdx.x;
    if (e < N_EDGES) atomicAdd(&deg[dst[e]], 1.0f);
}

__global__ void rsqrt_inplace_k(float* __restrict__ p, int n) {
    int i = blockIdx.x * blockDim.x + threadIdx.x;
    if (i < n) p[i] = rsqrtf(p[i]);
}

// ---------------- generic tiled fp32 GEMM: C[M,N] = A[M,K] @ B[K,N] ----------------
// BM=BN=64, BK=16, 256 threads, 4x4 micro-tile per thread.

__global__ __launch_bounds__(256) void gemm_k(const float* __restrict__ A,
                                              const float* __restrict__ B,
                                              float* __restrict__ C,
                                              int M, int N, int K) {
    __shared__ float As[16][66];
    __shared__ float Bs[16][66];
    const int bm = blockIdx.y * 64;
    const int bn = blockIdx.x * 64;
    const int tid = threadIdx.x;
    const int tx = tid & 15;        // 0..15 -> 4 cols each
    const int ty = tid >> 4;        // 0..15 -> 4 rows each
    float acc[4][4] = {};

    for (int k0 = 0; k0 < K; k0 += 16) {
        // A tile: 64 rows x 16 k, coalesced along K
        #pragma unroll
        for (int i = 0; i < 4; ++i) {
            int idx = tid + i * 256;          // 0..1023
            int kk = idx & 15;
            int r  = idx >> 4;
            int gr = bm + r, gk = k0 + kk;
            As[kk][r] = (gr < M && gk < K) ? A[(long long)gr * K + gk] : 0.0f;
        }
        // B tile: 16 k x 64 n, coalesced along N
        #pragma unroll
        for (int i = 0; i < 4; ++i) {
            int idx = tid + i * 256;
            int c  = idx & 63;
            int kk = idx >> 6;
            int gk = k0 + kk;
            Bs[kk][c] = (gk < K) ? B[(long long)gk * N + bn + c] : 0.0f;
        }
        __syncthreads();
        #pragma unroll
        for (int kk = 0; kk < 16; ++kk) {
            float a[4], b[4];
            #pragma unroll
            for (int i = 0; i < 4; ++i) a[i] = As[kk][ty * 4 + i];
            #pragma unroll
            for (int j = 0; j < 4; ++j) b[j] = Bs[kk][tx * 4 + j];
            #pragma unroll
            for (int i = 0; i < 4; ++i)
                #pragma unroll
                for (int j = 0; j < 4; ++j)
                    acc[i][j] += a[i] * b[j];
        }
        __syncthreads();
    }
    #pragma unroll
    for (int i = 0; i < 4; ++i) {
        int gr = bm + ty * 4 + i;
        if (gr < M) {
            #pragma unroll
            for (int j = 0; j < 4; ++j)
                C[(long long)gr * N + bn + tx * 4 + j] = acc[i][j];
        }
    }
}

// ---------------- aggregation ----------------

// out[i][f] = h[i][f] * dinv[i]^2 + bias[f]   (self-loop term + bias, full overwrite)
__global__ void self_bias_k(const float* __restrict__ h, const float* __restrict__ dinv,
                            const float* __restrict__ bias, float* __restrict__ out,
                            int fmask, int fshift) {
    long long gid = (long long)blockIdx.x * blockDim.x + threadIdx.x;
    long long total = (long long)N_NODES << fshift;
    if (gid >= total) return;
    int i = (int)(gid >> fshift);
    int f = (int)(gid & fmask);
    float di = dinv[i];
    out[gid] = h[gid] * di * di + bias[f];
}

// out[dst][f] += h[src][f] * dinv[src] * dinv[dst]
__global__ void scatter_k(const float* __restrict__ h, const int* __restrict__ src,
                          const int* __restrict__ dst, const float* __restrict__ dinv,
                          float* __restrict__ out, int fmask, int fshift) {
    long long gid = (long long)blockIdx.x * blockDim.x + threadIdx.x;
    long long total = (long long)N_EDGES << fshift;
    if (gid >= total) return;
    int e = (int)(gid >> fshift);
    int f = (int)(gid & fmask);
    int s = src[e], d = dst[e];
    float coef = dinv[s] * dinv[d];
    atomicAdd(&out[((long long)d << fshift) + f], h[((long long)s << fshift) + f] * coef);
}

__global__ void relu_k(float* __restrict__ p, long long n) {
    long long i = (long long)blockIdx.x * blockDim.x + threadIdx.x;
    if (i < n) p[i] = fmaxf(p[i], 0.0f);
}

// ---------------- pooling + MLP head ----------------

__global__ void zero_k(float* __restrict__ p, int n) {
    int i = blockIdx.x * blockDim.x + threadIdx.x;
    if (i < n) p[i] = 0.0f;
}

__global__ void pool_scatter_k(const float* __restrict__ h, const int* __restrict__ batch,
                               float* __restrict__ pool, float* __restrict__ cnt) {
    long long gid = (long long)blockIdx.x * blockDim.x + threadIdx.x;
    long long total = (long long)N_NODES * HID;
    if (gid >= total) return;
    int i = (int)(gid >> 7);
    int f = (int)(gid & 127);
    int g = batch[i];
    atomicAdd(&pool[g * HID + f], h[gid]);
    if (f == 0) atomicAdd(&cnt[g], 1.0f);
}

// one wave (64 threads) per graph: pooled = sum/cnt; relu(pooled@fw1+fb1); @fw2+fb2
__global__ __launch_bounds__(64) void mlp_head_k(const float* __restrict__ pool,
                                                 const float* __restrict__ cnt,
                                                 const float* __restrict__ fw1,
                                                 const float* __restrict__ fb1,
                                                 const float* __restrict__ fw2,
                                                 const float* __restrict__ fb2,
                                                 float* __restrict__ out) {
    __shared__ float ps[HID];
    int g = blockIdx.x;
    int t = threadIdx.x;  // 0..63
    float inv = 1.0f / fmaxf(cnt[g], 1.0f);
    ps[t]      = pool[g * HID + t] * inv;
    ps[t + 64] = pool[g * HID + 64 + t] * inv;
    __syncthreads();
    float acc = fb1[t];
    #pragma unroll 8
    for (int k = 0; k < HID; ++k) acc = fmaf(ps[k], fw1[k * 64 + t], acc);
    float v = fmaxf(acc, 0.0f) * fw2[t];
    #pragma unroll
    for (int off = 32; off > 0; off >>= 1) v += __shfl_down(v, off);
    if (t == 0) out[g] = v + fb2[0];
}

// ---------------- launch ----------------

extern "C" void kernel_launch(void* const* d_in, const int* in_sizes, int n_in,
                              void* d_out, int out_size, void* d_ws, size_t ws_size,
                              hipStream_t stream) {
    const float* x     = (const float*)d_in[0];
    const int*   ei    = (const int*)d_in[1];
    const int*   batch = (const int*)d_in[2];
    const float* W1 = (const float*)d_in[3];
    const float* b1 = (const float*)d_in[4];
    const float* W2 = (const float*)d_in[5];
    const float* b2 = (const float*)d_in[6];
    const float* W3 = (const float*)d_in[7];
    const float* b3 = (const float*)d_in[8];
    const float* fw1 = (const float*)d_in[9];
    const float* fb1 = (const float*)d_in[10];
    const float* fw2 = (const float*)d_in[11];
    const float* fb2 = (const float*)d_in[12];
    float* out = (float*)d_out;

    const int* src = ei;
    const int* dst = ei + N_EDGES;

    // workspace layout (floats)
    float* ws   = (float*)d_ws;
    float* dinv = ws;                          // 100000 (deg -> dinv in place)
    float* A    = ws + 100352;                 // up to 100000*256
    float* B    = A + (long long)N_NODES * 256;
    float* pool = B + (long long)N_NODES * 256;
    float* cnt  = pool + N_GRAPHS * HID;

    const int T = 256;
    // degrees
    init_ones_k<<<(N_NODES + T - 1) / T, T, 0, stream>>>(dinv, N_NODES);
    count_deg_k<<<(N_EDGES + T - 1) / T, T, 0, stream>>>(dst, dinv);
    rsqrt_inplace_k<<<(N_NODES + T - 1) / T, T, 0, stream>>>(dinv, N_NODES);

    struct Layer { const float* W; const float* b; int N; int K; int fshift; };
    Layer layers[3] = {
        {W1, b1, 128, NODE_F, 7},
        {W2, b2, 256, HID,    8},
        {W3, b3, 128, 2*HID,  7},
    };

    const float* in = x;
    for (int l = 0; l < 3; ++l) {
        int N = layers[l].N, K = layers[l].K;
        int fshift = layers[l].fshift, fmask = N - 1;
        dim3 ggrid(N / 64, (N_NODES + 63) / 64);
        gemm_k<<<ggrid, 256, 0, stream>>>(in, layers[l].W, A, N_NODES, N, K);

        long long nodeTot = (long long)N_NODES << fshift;
        self_bias_k<<<(int)((nodeTot + T - 1) / T), T, 0, stream>>>(A, dinv, layers[l].b, B, fmask, fshift);

        long long edgeTot = (long long)N_EDGES << fshift;
        scatter_k<<<(int)((edgeTot + T - 1) / T), T, 0, stream>>>(A, src, dst, dinv, B, fmask, fshift);

        relu_k<<<(int)((nodeTot + T - 1) / T), T, 0, stream>>>(B, nodeTot);
        in = B;
    }

    // pooling
    zero_k<<<(N_GRAPHS * HID + N_GRAPHS + T - 1) / T, T, 0, stream>>>(pool, N_GRAPHS * HID + N_GRAPHS);
    long long poolTot = (long long)N_NODES * HID;
    pool_scatter_k<<<(int)((poolTot + T - 1) / T), T, 0, stream>>>(B, batch, pool, cnt);

    mlp_head_k<<<N_GRAPHS, 64, 0, stream>>>(pool, cnt, fw1, fb1, fw2, fb2, out);
}

// Round 2
// 770.889 us; speedup vs baseline: 1.8171x; 1.8171x over previous
//
#include <hip/hip_runtime.h>

#define N_NODES 100000
#define N_EDGES 400000
#define N_GRAPHS 2000
#define NODE_F 78
#define HID 128
#define PAD 32

// ---------------- CSR build ----------------

__global__ void zero_int_k(int* __restrict__ p, int n) {
    int i = blockIdx.x * blockDim.x + threadIdx.x;
    if (i < n) p[i] = 0;
}

__global__ void fill_csr_k(const int* __restrict__ src, const int* __restrict__ dst,
                           int* __restrict__ cursor, int* __restrict__ csr) {
    int e = blockIdx.x * blockDim.x + threadIdx.x;
    if (e >= N_EDGES) return;
    int s = src[e], d = dst[e];
    int p = atomicAdd(&cursor[d], 1);
    if (p < PAD) csr[d * PAD + p] = s;
}

__global__ void dinv_k(const int* __restrict__ deg, float* __restrict__ dinv, int n) {
    int i = blockIdx.x * blockDim.x + threadIdx.x;
    if (i < n) dinv[i] = rsqrtf((float)deg[i] + 1.0f);  // +1 self-loop
}

// ---------------- generic tiled fp32 GEMM: C[M,N] = A[M,K] @ B[K,N] ----------------

__global__ __launch_bounds__(256) void gemm_k(const float* __restrict__ A,
                                              const float* __restrict__ B,
                                              float* __restrict__ C,
                                              int M, int N, int K) {
    __shared__ float As[16][66];
    __shared__ float Bs[16][66];
    const int bm = blockIdx.y * 64;
    const int bn = blockIdx.x * 64;
    const int tid = threadIdx.x;
    const int tx = tid & 15;
    const int ty = tid >> 4;
    float acc[4][4] = {};

    for (int k0 = 0; k0 < K; k0 += 16) {
        #pragma unroll
        for (int i = 0; i < 4; ++i) {
            int idx = tid + i * 256;
            int kk = idx & 15;
            int r  = idx >> 4;
            int gr = bm + r, gk = k0 + kk;
            As[kk][r] = (gr < M && gk < K) ? A[(long long)gr * K + gk] : 0.0f;
        }
        #pragma unroll
        for (int i = 0; i < 4; ++i) {
            int idx = tid + i * 256;
            int c  = idx & 63;
            int kk = idx >> 6;
            int gk = k0 + kk;
            Bs[kk][c] = (gk < K) ? B[(long long)gk * N + bn + c] : 0.0f;
        }
        __syncthreads();
        #pragma unroll
        for (int kk = 0; kk < 16; ++kk) {
            float a[4], b[4];
            #pragma unroll
            for (int i = 0; i < 4; ++i) a[i] = As[kk][ty * 4 + i];
            #pragma unroll
            for (int j = 0; j < 4; ++j) b[j] = Bs[kk][tx * 4 + j];
            #pragma unroll
            for (int i = 0; i < 4; ++i)
                #pragma unroll
                for (int j = 0; j < 4; ++j)
                    acc[i][j] += a[i] * b[j];
        }
        __syncthreads();
    }
    #pragma unroll
    for (int i = 0; i < 4; ++i) {
        int gr = bm + ty * 4 + i;
        if (gr < M) {
            #pragma unroll
            for (int j = 0; j < 4; ++j)
                C[(long long)gr * N + bn + tx * 4 + j] = acc[i][j];
        }
    }
}

// ---------------- fused gather aggregation: out = relu(agg + bias) ----------------
// One wave per node. NF=128 -> float2/lane, NF=256 -> float4/lane.

template <int NF>
__global__ __launch_bounds__(256) void gather_k(const float* __restrict__ A,
                                                const int* __restrict__ csr,
                                                const int* __restrict__ deg,
                                                const float* __restrict__ dinv,
                                                const float* __restrict__ bias,
                                                float* __restrict__ out) {
    constexpr int VPL = NF / 64;  // floats per lane
    int wid = (blockIdx.x * blockDim.x + threadIdx.x) >> 6;  // global wave id = node
    int lane = threadIdx.x & 63;
    if (wid >= N_NODES) return;
    const int node = wid;

    float di = dinv[node];
    float acc[VPL];
    {
        const float* row = A + (long long)node * NF + lane * VPL;
        float sc = di * di;
        #pragma unroll
        for (int k = 0; k < VPL; ++k) acc[k] = row[k] * sc;
    }
    int d = deg[node];
    if (d > PAD) d = PAD;
    const int* e = csr + node * PAD;
    for (int j = 0; j < d; ++j) {
        int s = e[j];
        float c = di * dinv[s];
        const float* row = A + (long long)s * NF + lane * VPL;
        if (VPL == 2) {
            float2 v = *reinterpret_cast<const float2*>(row);
            acc[0] += v.x * c;
            acc[1] += v.y * c;
        } else {
            float4 v = *reinterpret_cast<const float4*>(row);
            acc[0] += v.x * c;
            acc[1] += v.y * c;
            acc[2] += v.z * c;
            acc[3] += v.w * c;
        }
    }
    float* orow = out + (long long)node * NF + lane * VPL;
    #pragma unroll
    for (int k = 0; k < VPL; ++k)
        orow[k] = fmaxf(acc[k] + bias[lane * VPL + k], 0.0f);
}

// ---------------- pooling + MLP head ----------------

__global__ void zero_k(float* __restrict__ p, int n) {
    int i = blockIdx.x * blockDim.x + threadIdx.x;
    if (i < n) p[i] = 0.0f;
}

__global__ void pool_scatter_k(const float* __restrict__ h, const int* __restrict__ batch,
                               float* __restrict__ pool, float* __restrict__ cnt) {
    long long gid = (long long)blockIdx.x * blockDim.x + threadIdx.x;
    long long total = (long long)N_NODES * HID;
    if (gid >= total) return;
    int i = (int)(gid >> 7);
    int f = (int)(gid & 127);
    int g = batch[i];
    atomicAdd(&pool[g * HID + f], h[gid]);
    if (f == 0) atomicAdd(&cnt[g], 1.0f);
}

__global__ __launch_bounds__(64) void mlp_head_k(const float* __restrict__ pool,
                                                 const float* __restrict__ cnt,
                                                 const float* __restrict__ fw1,
                                                 const float* __restrict__ fb1,
                                                 const float* __restrict__ fw2,
                                                 const float* __restrict__ fb2,
                                                 float* __restrict__ out) {
    __shared__ float ps[HID];
    int g = blockIdx.x;
    int t = threadIdx.x;
    float inv = 1.0f / fmaxf(cnt[g], 1.0f);
    ps[t]      = pool[g * HID + t] * inv;
    ps[t + 64] = pool[g * HID + 64 + t] * inv;
    __syncthreads();
    float acc = fb1[t];
    #pragma unroll 8
    for (int k = 0; k < HID; ++k) acc = fmaf(ps[k], fw1[k * 64 + t], acc);
    float v = fmaxf(acc, 0.0f) * fw2[t];
    #pragma unroll
    for (int off = 32; off > 0; off >>= 1) v += __shfl_down(v, off);
    if (t == 0) out[g] = v + fb2[0];
}

// ---------------- launch ----------------

extern "C" void kernel_launch(void* const* d_in, const int* in_sizes, int n_in,
                              void* d_out, int out_size, void* d_ws, size_t ws_size,
                              hipStream_t stream) {
    const float* x     = (const float*)d_in[0];
    const int*   ei    = (const int*)d_in[1];
    const int*   batch = (const int*)d_in[2];
    const float* W1 = (const float*)d_in[3];
    const float* b1 = (const float*)d_in[4];
    const float* W2 = (const float*)d_in[5];
    const float* b2 = (const float*)d_in[6];
    const float* W3 = (const float*)d_in[7];
    const float* b3 = (const float*)d_in[8];
    const float* fw1 = (const float*)d_in[9];
    const float* fb1 = (const float*)d_in[10];
    const float* fw2 = (const float*)d_in[11];
    const float* fb2 = (const float*)d_in[12];
    float* out = (float*)d_out;

    const int* src = ei;
    const int* dst = ei + N_EDGES;

    // workspace layout
    float* ws    = (float*)d_ws;
    float* dinv  = ws;                              // 100352 floats
    int*   cur   = (int*)(ws + 100352);             // 100352 ints (cursor -> in-degree)
    int*   csr   = cur + 100352;                    // 100000*PAD ints
    float* buf0  = (float*)(csr + N_NODES * PAD);   // 25.6M floats
    float* buf1  = buf0 + (long long)N_NODES * 256;
    float* pool  = buf1 + (long long)N_NODES * 256;
    float* cnt   = pool + N_GRAPHS * HID;

    const int T = 256;

    // CSR build + dinv
    zero_int_k<<<(N_NODES + T - 1) / T, T, 0, stream>>>(cur, N_NODES);
    fill_csr_k<<<(N_EDGES + T - 1) / T, T, 0, stream>>>(src, dst, cur, csr);
    dinv_k<<<(N_NODES + T - 1) / T, T, 0, stream>>>(cur, dinv, N_NODES);

    // layer 1: x[100000,78] @ W1[78,128]
    gemm_k<<<dim3(128 / 64, (N_NODES + 63) / 64), 256, 0, stream>>>(x, W1, buf0, N_NODES, 128, NODE_F);
    gather_k<128><<<(N_NODES * 64 + T - 1) / T, T, 0, stream>>>(buf0, csr, cur, dinv, b1, buf1);

    // layer 2: [100000,128] @ W2[128,256]
    gemm_k<<<dim3(256 / 64, (N_NODES + 63) / 64), 256, 0, stream>>>(buf1, W2, buf0, N_NODES, 256, HID);
    gather_k<256><<<(N_NODES * 64 + T - 1) / T, T, 0, stream>>>(buf0, csr, cur, dinv, b2, buf1);

    // layer 3: [100000,256] @ W3[256,128]
    gemm_k<<<dim3(128 / 64, (N_NODES + 63) / 64), 256, 0, stream>>>(buf1, W3, buf0, N_NODES, 128, 2 * HID);
    gather_k<128><<<(N_NODES * 64 + T - 1) / T, T, 0, stream>>>(buf0, csr, cur, dinv, b3, buf1);

    // pooling + head
    zero_k<<<(N_GRAPHS * HID + N_GRAPHS + T - 1) / T, T, 0, stream>>>(pool, N_GRAPHS * HID + N_GRAPHS);
    long long poolTot = (long long)N_NODES * HID;
    pool_scatter_k<<<(int)((poolTot + T - 1) / T), T, 0, stream>>>(buf1, batch, pool, cnt);

    mlp_head_k<<<N_GRAPHS, 64, 0, stream>>>(pool, cnt, fw1, fb1, fw2, fb2, out);
}

// Round 3
// 555.324 us; speedup vs baseline: 2.5225x; 1.3882x over previous
//
#include <hip/hip_runtime.h>

#define N_NODES 100000
#define N_EDGES 400000
#define N_GRAPHS 2000
#define NODE_F 78
#define HID 128
#define PAD 32

typedef __attribute__((ext_vector_type(8))) short short8v;
typedef __attribute__((ext_vector_type(4))) float f32x4;

__device__ __forceinline__ ushort f2bf(float f) {
    unsigned u = __float_as_uint(f);
    unsigned r = (u + 0x7FFFu + ((u >> 16) & 1u)) >> 16;  // round-to-nearest-even
    return (ushort)r;
}
__device__ __forceinline__ float bf2f(ushort b) {
    return __uint_as_float(((unsigned)b) << 16);
}

// ---------------- CSR build ----------------

__global__ void zero_int_k(int* __restrict__ p, int n) {
    int i = blockIdx.x * blockDim.x + threadIdx.x;
    if (i < n) p[i] = 0;
}

__global__ void fill_csr_k(const int* __restrict__ src, const int* __restrict__ dst,
                           int* __restrict__ cursor, int* __restrict__ csr) {
    int e = blockIdx.x * blockDim.x + threadIdx.x;
    if (e >= N_EDGES) return;
    int s = src[e], d = dst[e];
    int p = atomicAdd(&cursor[d], 1);
    if (p < PAD) csr[d * PAD + p] = s;
}

__global__ void dinv_k(const int* __restrict__ deg, float* __restrict__ dinv, int n) {
    int i = blockIdx.x * blockDim.x + threadIdx.x;
    if (i < n) dinv[i] = rsqrtf((float)deg[i] + 1.0f);
}

// ---------------- weight prep: W[K][N] fp32 -> Wt hi/lo bf16 [N][256], zero-padded ----------------

__global__ void prep_wt_k(const float* __restrict__ W, ushort* __restrict__ Wth,
                          ushort* __restrict__ Wtl, int K, int N) {
    int idx = blockIdx.x * blockDim.x + threadIdx.x;
    if (idx >= N * 256) return;
    int n = idx >> 8, k = idx & 255;
    float v = (k < K) ? W[(long long)k * N + n] : 0.0f;
    ushort h = f2bf(v);
    ushort l = f2bf(v - bf2f(h));
    Wth[n * 256 + k] = h;
    Wtl[n * 256 + k] = l;
}

// ---------------- split-bf16 MFMA GEMM: C[M,N] = A[M,(lda,K)] @ W[K,N] ----------------
// BM=128, BN=128, BK=64. 256 threads = 4 waves; wave w owns rows w*32..w*32+31.
// LDS XOR-swizzle: 8-elem k-slot s stored at s ^ (row&7) -> conflict-free ds_read_b128.

template <bool BIAS_RELU>
__global__ __launch_bounds__(256) void gemm_mfma_k(
        const float* __restrict__ A, int lda, int K, int M,
        const ushort* __restrict__ Wth, const ushort* __restrict__ Wtl,
        const float* __restrict__ bias, float* __restrict__ C, int N) {
    __shared__ ushort Ah[128 * 64];
    __shared__ ushort Al[128 * 64];
    __shared__ ushort Bh[128 * 64];
    __shared__ ushort Bl[128 * 64];
    const int tid = threadIdx.x;
    const int w = tid >> 6, l = tid & 63;
    const int bm = blockIdx.x * 128;
    const int bn = blockIdx.y * 128;

    f32x4 acc[2][8];
    #pragma unroll
    for (int m = 0; m < 2; ++m)
        #pragma unroll
        for (int j = 0; j < 8; ++j)
            acc[m][j] = (f32x4){0.f, 0.f, 0.f, 0.f};

    for (int k0 = 0; k0 < K; k0 += 64) {
        __syncthreads();
        // ---- stage A tile 128x64 (fp32 -> bf16 hi/lo), 8 float4 tasks per thread ----
        #pragma unroll
        for (int i = 0; i < 8; ++i) {
            int idx = tid + i * 256;
            int r = idx >> 4;
            int kq = (idx & 15) * 4;
            ushort4 h4, l4;
            if (k0 + kq < K) {
                int gr = bm + r; if (gr >= M) gr = M - 1;
                float4 v = *reinterpret_cast<const float4*>(&A[(long long)gr * lda + k0 + kq]);
                float f0 = v.x, f1 = v.y, f2 = v.z, f3 = v.w;
                h4.x = f2bf(f0); l4.x = f2bf(f0 - bf2f(h4.x));
                h4.y = f2bf(f1); l4.y = f2bf(f1 - bf2f(h4.y));
                h4.z = f2bf(f2); l4.z = f2bf(f2 - bf2f(h4.z));
                h4.w = f2bf(f3); l4.w = f2bf(f3 - bf2f(h4.w));
            } else {
                h4 = (ushort4){0, 0, 0, 0};
                l4 = (ushort4){0, 0, 0, 0};
            }
            int e = r * 64 + ((kq >> 3) ^ (r & 7)) * 8 + (kq & 7);
            *reinterpret_cast<ushort4*>(&Ah[e]) = h4;
            *reinterpret_cast<ushort4*>(&Al[e]) = l4;
        }
        // ---- stage B tile 128n x 64k from preconverted Wt[n][256], 4 tasks per thread ----
        #pragma unroll
        for (int i = 0; i < 4; ++i) {
            int idx = tid + i * 256;
            int n = idx >> 3, s0 = idx & 7;
            long long g = (long long)(bn + n) * 256 + k0 + s0 * 8;
            short8v vh = *reinterpret_cast<const short8v*>(&Wth[g]);
            short8v vl = *reinterpret_cast<const short8v*>(&Wtl[g]);
            int e = n * 64 + (s0 ^ (n & 7)) * 8;
            *reinterpret_cast<short8v*>(&Bh[e]) = vh;
            *reinterpret_cast<short8v*>(&Bl[e]) = vl;
        }
        __syncthreads();
        // ---- compute: 2 k-substeps of 32, 8 n-tiles, 2 m-tiles, 3 split products ----
        #pragma unroll
        for (int ks = 0; ks < 2; ++ks) {
            short8v ah[2], al[2];
            #pragma unroll
            for (int m = 0; m < 2; ++m) {
                int r = w * 32 + m * 16 + (l & 15);
                int e = r * 64 + (((ks * 4 + (l >> 4))) ^ (r & 7)) * 8;
                ah[m] = *reinterpret_cast<const short8v*>(&Ah[e]);
                al[m] = *reinterpret_cast<const short8v*>(&Al[e]);
            }
            #pragma unroll
            for (int j = 0; j < 8; ++j) {
                int n = j * 16 + (l & 15);
                int e = n * 64 + (((ks * 4 + (l >> 4))) ^ (n & 7)) * 8;
                short8v bh = *reinterpret_cast<const short8v*>(&Bh[e]);
                short8v bl = *reinterpret_cast<const short8v*>(&Bl[e]);
                #pragma unroll
                for (int m = 0; m < 2; ++m) {
                    acc[m][j] = __builtin_amdgcn_mfma_f32_16x16x32_bf16(ah[m], bh, acc[m][j], 0, 0, 0);
                    acc[m][j] = __builtin_amdgcn_mfma_f32_16x16x32_bf16(ah[m], bl, acc[m][j], 0, 0, 0);
                    acc[m][j] = __builtin_amdgcn_mfma_f32_16x16x32_bf16(al[m], bh, acc[m][j], 0, 0, 0);
                }
            }
        }
    }

    // ---- epilogue: C/D layout col=lane&15, row=(lane>>4)*4+reg ----
    #pragma unroll
    for (int j = 0; j < 8; ++j) {
        int gc = bn + j * 16 + (l & 15);
        float bv = 0.0f;
        if (BIAS_RELU) bv = bias[gc];
        #pragma unroll
        for (int m = 0; m < 2; ++m) {
            #pragma unroll
            for (int rg = 0; rg < 4; ++rg) {
                int gr = bm + w * 32 + m * 16 + (l >> 4) * 4 + rg;
                if (gr < M) {
                    float v = acc[m][j][rg] + bv;
                    if (BIAS_RELU) v = fmaxf(v, 0.0f);
                    C[(long long)gr * N + gc] = v;
                }
            }
        }
    }
}

// ---------------- gathers ----------------

// aggregate raw x [N,78] -> out [N,80] (cols 78,79 = 0), no bias/relu
__global__ __launch_bounds__(256) void gather78_k(const float* __restrict__ X,
        const int* __restrict__ csr, const int* __restrict__ deg,
        const float* __restrict__ dinv, float* __restrict__ out) {
    int wid = (blockIdx.x * blockDim.x + threadIdx.x) >> 6;
    int lane = threadIdx.x & 63;
    if (wid >= N_NODES) return;
    float di = dinv[wid];
    float ax = 0.f, ay = 0.f;
    bool act = lane < 39;
    if (act) {
        float2 v = *reinterpret_cast<const float2*>(&X[(long long)wid * 78 + lane * 2]);
        float sc = di * di;
        ax = v.x * sc; ay = v.y * sc;
    }
    int d = deg[wid]; if (d > PAD) d = PAD;
    const int* e = csr + wid * PAD;
    for (int j = 0; j < d; ++j) {
        int s = e[j];
        float c = di * dinv[s];
        if (act) {
            float2 v = *reinterpret_cast<const float2*>(&X[(long long)s * 78 + lane * 2]);
            ax += v.x * c; ay += v.y * c;
        }
    }
    if (lane < 40)
        *reinterpret_cast<float2*>(&out[(long long)wid * 80 + lane * 2]) = make_float2(ax, ay);
}

// aggregate [N,128] -> [N,128]; optional bias+relu
template <bool BIAS_RELU>
__global__ __launch_bounds__(256) void gather128_k(const float* __restrict__ A,
        const int* __restrict__ csr, const int* __restrict__ deg,
        const float* __restrict__ dinv, const float* __restrict__ bias,
        float* __restrict__ out) {
    int wid = (blockIdx.x * blockDim.x + threadIdx.x) >> 6;
    int lane = threadIdx.x & 63;
    if (wid >= N_NODES) return;
    float di = dinv[wid];
    float2 v0 = *reinterpret_cast<const float2*>(&A[(long long)wid * 128 + lane * 2]);
    float sc = di * di;
    float ax = v0.x * sc, ay = v0.y * sc;
    int d = deg[wid]; if (d > PAD) d = PAD;
    const int* e = csr + wid * PAD;
    for (int j = 0; j < d; ++j) {
        int s = e[j];
        float c = di * dinv[s];
        float2 v = *reinterpret_cast<const float2*>(&A[(long long)s * 128 + lane * 2]);
        ax += v.x * c; ay += v.y * c;
    }
    if (BIAS_RELU) {
        ax = fmaxf(ax + bias[lane * 2], 0.f);
        ay = fmaxf(ay + bias[lane * 2 + 1], 0.f);
    }
    *reinterpret_cast<float2*>(&out[(long long)wid * 128 + lane * 2]) = make_float2(ax, ay);
}

// ---------------- pooling + MLP head ----------------

__global__ void zero_k(float* __restrict__ p, int n) {
    int i = blockIdx.x * blockDim.x + threadIdx.x;
    if (i < n) p[i] = 0.0f;
}

__global__ void pool_scatter_k(const float* __restrict__ h, const int* __restrict__ batch,
                               float* __restrict__ pool, float* __restrict__ cnt) {
    long long gid = (long long)blockIdx.x * blockDim.x + threadIdx.x;
    long long total = (long long)N_NODES * HID;
    if (gid >= total) return;
    int i = (int)(gid >> 7);
    int f = (int)(gid & 127);
    int g = batch[i];
    atomicAdd(&pool[g * HID + f], h[gid]);
    if (f == 0) atomicAdd(&cnt[g], 1.0f);
}

__global__ __launch_bounds__(64) void mlp_head_k(const float* __restrict__ pool,
                                                 const float* __restrict__ cnt,
                                                 const float* __restrict__ fw1,
                                                 const float* __restrict__ fb1,
                                                 const float* __restrict__ fw2,
                                                 const float* __restrict__ fb2,
                                                 float* __restrict__ out) {
    __shared__ float ps[HID];
    int g = blockIdx.x;
    int t = threadIdx.x;
    float inv = 1.0f / fmaxf(cnt[g], 1.0f);
    ps[t]      = pool[g * HID + t] * inv;
    ps[t + 64] = pool[g * HID + 64 + t] * inv;
    __syncthreads();
    float acc = fb1[t];
    #pragma unroll 8
    for (int k = 0; k < HID; ++k) acc = fmaf(ps[k], fw1[k * 64 + t], acc);
    float v = fmaxf(acc, 0.0f) * fw2[t];
    #pragma unroll
    for (int off = 32; off > 0; off >>= 1) v += __shfl_down(v, off);
    if (t == 0) out[g] = v + fb2[0];
}

// ---------------- launch ----------------

extern "C" void kernel_launch(void* const* d_in, const int* in_sizes, int n_in,
                              void* d_out, int out_size, void* d_ws, size_t ws_size,
                              hipStream_t stream) {
    const float* x     = (const float*)d_in[0];
    const int*   ei    = (const int*)d_in[1];
    const int*   batch = (const int*)d_in[2];
    const float* W1 = (const float*)d_in[3];
    const float* b1 = (const float*)d_in[4];
    const float* W2 = (const float*)d_in[5];
    const float* b2 = (const float*)d_in[6];
    const float* W3 = (const float*)d_in[7];
    const float* b3 = (const float*)d_in[8];
    const float* fw1 = (const float*)d_in[9];
    const float* fb1 = (const float*)d_in[10];
    const float* fw2 = (const float*)d_in[11];
    const float* fb2 = (const float*)d_in[12];
    float* out = (float*)d_out;

    const int* src = ei;
    const int* dst = ei + N_EDGES;

    // workspace layout (R0 region aliases: {xpad 32MB | bufA 51.2MB | spare} == bufW 102.4MB)
    char* p = (char*)d_ws;
    float* dinv = (float*)p;  p += 100352 * 4;
    int*   cur  = (int*)p;    p += 100352 * 4;
    int*   csr  = (int*)p;    p += (size_t)N_NODES * PAD * 4;
    ushort* wth = (ushort*)p; p += 256 * 256 * 2;
    ushort* wtl = (ushort*)p; p += 256 * 256 * 2;
    float* bufW = (float*)p;                              // 100000*256 floats
    float* xpad = bufW;                                   // 100000*80
    float* bufA = (float*)(p + (size_t)N_NODES * 80 * 4); // 100000*128
    p += (size_t)N_NODES * 256 * 4;
    float* bufB = (float*)p;  p += (size_t)N_NODES * 128 * 4;
    float* pool = (float*)p;  p += (size_t)N_GRAPHS * HID * 4;
    float* cnt  = (float*)p;

    const int T = 256;
    const int gw = (N_NODES * 64 + T - 1) / T;  // one wave per node

    // CSR + dinv
    zero_int_k<<<(N_NODES + T - 1) / T, T, 0, stream>>>(cur, N_NODES);
    fill_csr_k<<<(N_EDGES + T - 1) / T, T, 0, stream>>>(src, dst, cur, csr);
    dinv_k<<<(N_NODES + T - 1) / T, T, 0, stream>>>(cur, dinv, N_NODES);

    // layer 1: gather-first on 78 feats, then GEMM (K=80 padded) with bias+relu
    gather78_k<<<gw, T, 0, stream>>>(x, csr, cur, dinv, xpad);
    prep_wt_k<<<(128 * 256 + T - 1) / T, T, 0, stream>>>(W1, wth, wtl, NODE_F, 128);
    gemm_mfma_k<true><<<dim3(782, 1), 256, 0, stream>>>(xpad, 80, 80, N_NODES, wth, wtl, b1, bufA, 128);

    // layer 2: gather-first on 128 feats, then GEMM 128->256 with bias+relu
    gather128_k<false><<<gw, T, 0, stream>>>(bufA, csr, cur, dinv, nullptr, bufB);
    prep_wt_k<<<(256 * 256 + T - 1) / T, T, 0, stream>>>(W2, wth, wtl, HID, 256);
    gemm_mfma_k<true><<<dim3(782, 2), 256, 0, stream>>>(bufB, 128, 128, N_NODES, wth, wtl, b2, bufW, 256);

    // layer 3: GEMM 256->128 plain, then gather with bias+relu
    prep_wt_k<<<(128 * 256 + T - 1) / T, T, 0, stream>>>(W3, wth, wtl, 2 * HID, 128);
    gemm_mfma_k<false><<<dim3(782, 1), 256, 0, stream>>>(bufW, 256, 256, N_NODES, wth, wtl, nullptr, bufB, 128);
    gather128_k<true><<<gw, T, 0, stream>>>(bufB, csr, cur, dinv, b3, bufA);

    // pooling + head
    zero_k<<<(N_GRAPHS * HID + N_GRAPHS + T - 1) / T, T, 0, stream>>>(pool, N_GRAPHS * HID + N_GRAPHS);
    long long poolTot = (long long)N_NODES * HID;
    pool_scatter_k<<<(int)((poolTot + T - 1) / T), T, 0, stream>>>(bufA, batch, pool, cnt);

    mlp_head_k<<<N_GRAPHS, 64, 0, stream>>>(pool, cnt, fw1, fb1, fw2, fb2, out);
}

// Round 4
// 454.377 us; speedup vs baseline: 3.0829x; 1.2222x over previous
//
#include <hip/hip_runtime.h>

#define N_NODES 100000
#define N_EDGES 400000
#define N_GRAPHS 2000
#define NODE_F 78
#define HID 128
#define PAD 32

typedef __attribute__((ext_vector_type(8))) short short8v;
typedef __attribute__((ext_vector_type(4))) float f32x4;

__device__ __forceinline__ ushort f2bf(float f) {
    unsigned u = __float_as_uint(f);
    unsigned r = (u + 0x7FFFu + ((u >> 16) & 1u)) >> 16;  // round-to-nearest-even
    return (ushort)r;
}
__device__ __forceinline__ float bf2f(ushort b) {
    return __uint_as_float(((unsigned)b) << 16);
}

// ---------------- CSR build ----------------

__global__ void zero_int_k(int* __restrict__ p, int n) {
    int i = blockIdx.x * blockDim.x + threadIdx.x;
    if (i < n) p[i] = 0;
}

__global__ void fill_csr_k(const int* __restrict__ src, const int* __restrict__ dst,
                           int* __restrict__ cursor, int* __restrict__ csr) {
    int e = blockIdx.x * blockDim.x + threadIdx.x;
    if (e >= N_EDGES) return;
    int s = src[e], d = dst[e];
    int p = atomicAdd(&cursor[d], 1);
    if (p < PAD) csr[d * PAD + p] = s;
}

__global__ void dinv_k(const int* __restrict__ deg, float* __restrict__ dinv, int n) {
    int i = blockIdx.x * blockDim.x + threadIdx.x;
    if (i < n) dinv[i] = rsqrtf((float)deg[i] + 1.0f);
}

// ---------------- weight prep: W[K][N] fp32 -> Wt hi/lo bf16 [N][256], zero-padded ----------------

__global__ void prep_wt_k(const float* __restrict__ W, ushort* __restrict__ Wth,
                          ushort* __restrict__ Wtl, int K, int N) {
    int idx = blockIdx.x * blockDim.x + threadIdx.x;
    if (idx >= N * 256) return;
    int n = idx >> 8, k = idx & 255;
    float v = (k < K) ? W[(long long)k * N + n] : 0.0f;
    ushort h = f2bf(v);
    ushort l = f2bf(v - bf2f(h));
    Wth[n * 256 + k] = h;
    Wtl[n * 256 + k] = l;
}

// ---------------- split-bf16 MFMA GEMM: C[M,N] = A[M,(lda,K)] @ W[K,N] ----------------

template <bool BIAS_RELU>
__global__ __launch_bounds__(256) void gemm_mfma_k(
        const float* __restrict__ A, int lda, int K, int M,
        const ushort* __restrict__ Wth, const ushort* __restrict__ Wtl,
        const float* __restrict__ bias, float* __restrict__ C, int N) {
    __shared__ ushort Ah[128 * 64];
    __shared__ ushort Al[128 * 64];
    __shared__ ushort Bh[128 * 64];
    __shared__ ushort Bl[128 * 64];
    const int tid = threadIdx.x;
    const int w = tid >> 6, l = tid & 63;
    const int bm = blockIdx.x * 128;
    const int bn = blockIdx.y * 128;

    f32x4 acc[2][8];
    #pragma unroll
    for (int m = 0; m < 2; ++m)
        #pragma unroll
        for (int j = 0; j < 8; ++j)
            acc[m][j] = (f32x4){0.f, 0.f, 0.f, 0.f};

    for (int k0 = 0; k0 < K; k0 += 64) {
        __syncthreads();
        #pragma unroll
        for (int i = 0; i < 8; ++i) {
            int idx = tid + i * 256;
            int r = idx >> 4;
            int kq = (idx & 15) * 4;
            ushort4 h4, l4;
            if (k0 + kq < K) {
                int gr = bm + r; if (gr >= M) gr = M - 1;
                float4 v = *reinterpret_cast<const float4*>(&A[(long long)gr * lda + k0 + kq]);
                float f0 = v.x, f1 = v.y, f2 = v.z, f3 = v.w;
                h4.x = f2bf(f0); l4.x = f2bf(f0 - bf2f(h4.x));
                h4.y = f2bf(f1); l4.y = f2bf(f1 - bf2f(h4.y));
                h4.z = f2bf(f2); l4.z = f2bf(f2 - bf2f(h4.z));
                h4.w = f2bf(f3); l4.w = f2bf(f3 - bf2f(h4.w));
            } else {
                h4 = (ushort4){0, 0, 0, 0};
                l4 = (ushort4){0, 0, 0, 0};
            }
            int e = r * 64 + ((kq >> 3) ^ (r & 7)) * 8 + (kq & 7);
            *reinterpret_cast<ushort4*>(&Ah[e]) = h4;
            *reinterpret_cast<ushort4*>(&Al[e]) = l4;
        }
        #pragma unroll
        for (int i = 0; i < 4; ++i) {
            int idx = tid + i * 256;
            int n = idx >> 3, s0 = idx & 7;
            long long g = (long long)(bn + n) * 256 + k0 + s0 * 8;
            short8v vh = *reinterpret_cast<const short8v*>(&Wth[g]);
            short8v vl = *reinterpret_cast<const short8v*>(&Wtl[g]);
            int e = n * 64 + (s0 ^ (n & 7)) * 8;
            *reinterpret_cast<short8v*>(&Bh[e]) = vh;
            *reinterpret_cast<short8v*>(&Bl[e]) = vl;
        }
        __syncthreads();
        #pragma unroll
        for (int ks = 0; ks < 2; ++ks) {
            short8v ah[2], al[2];
            #pragma unroll
            for (int m = 0; m < 2; ++m) {
                int r = w * 32 + m * 16 + (l & 15);
                int e = r * 64 + (((ks * 4 + (l >> 4))) ^ (r & 7)) * 8;
                ah[m] = *reinterpret_cast<const short8v*>(&Ah[e]);
                al[m] = *reinterpret_cast<const short8v*>(&Al[e]);
            }
            #pragma unroll
            for (int j = 0; j < 8; ++j) {
                int n = j * 16 + (l & 15);
                int e = n * 64 + (((ks * 4 + (l >> 4))) ^ (n & 7)) * 8;
                short8v bh = *reinterpret_cast<const short8v*>(&Bh[e]);
                short8v bl = *reinterpret_cast<const short8v*>(&Bl[e]);
                #pragma unroll
                for (int m = 0; m < 2; ++m) {
                    acc[m][j] = __builtin_amdgcn_mfma_f32_16x16x32_bf16(ah[m], bh, acc[m][j], 0, 0, 0);
                    acc[m][j] = __builtin_amdgcn_mfma_f32_16x16x32_bf16(ah[m], bl, acc[m][j], 0, 0, 0);
                    acc[m][j] = __builtin_amdgcn_mfma_f32_16x16x32_bf16(al[m], bh, acc[m][j], 0, 0, 0);
                }
            }
        }
    }

    #pragma unroll
    for (int j = 0; j < 8; ++j) {
        int gc = bn + j * 16 + (l & 15);
        float bv = 0.0f;
        if (BIAS_RELU) bv = bias[gc];
        #pragma unroll
        for (int m = 0; m < 2; ++m) {
            #pragma unroll
            for (int rg = 0; rg < 4; ++rg) {
                int gr = bm + w * 32 + m * 16 + (l >> 4) * 4 + rg;
                if (gr < M) {
                    float v = acc[m][j][rg] + bv;
                    if (BIAS_RELU) v = fmaxf(v, 0.0f);
                    C[(long long)gr * N + gc] = v;
                }
            }
        }
    }
}

// ---------------- gathers ----------------

// aggregate raw x [N,78] -> out [N,80] (cols 78,79 = 0), no bias/relu
__global__ __launch_bounds__(256) void gather78_k(const float* __restrict__ X,
        const int* __restrict__ csr, const int* __restrict__ deg,
        const float* __restrict__ dinv, float* __restrict__ out) {
    int wid = (blockIdx.x * blockDim.x + threadIdx.x) >> 6;
    int lane = threadIdx.x & 63;
    if (wid >= N_NODES) return;
    float di = dinv[wid];
    float ax = 0.f, ay = 0.f;
    bool act = lane < 39;
    if (act) {
        float2 v = *reinterpret_cast<const float2*>(&X[(long long)wid * 78 + lane * 2]);
        float sc = di * di;
        ax = v.x * sc; ay = v.y * sc;
    }
    int d = deg[wid]; if (d > PAD) d = PAD;
    const int* e = csr + wid * PAD;
    for (int j = 0; j < d; ++j) {
        int s = e[j];
        float c = di * dinv[s];
        if (act) {
            float2 v = *reinterpret_cast<const float2*>(&X[(long long)s * 78 + lane * 2]);
            ax += v.x * c; ay += v.y * c;
        }
    }
    if (lane < 40)
        *reinterpret_cast<float2*>(&out[(long long)wid * 80 + lane * 2]) = make_float2(ax, ay);
}

// aggregate [N,128] -> [N,128], no bias/relu (used before layer-2 GEMM)
__global__ __launch_bounds__(256) void gather128_k(const float* __restrict__ A,
        const int* __restrict__ csr, const int* __restrict__ deg,
        const float* __restrict__ dinv, float* __restrict__ out) {
    int wid = (blockIdx.x * blockDim.x + threadIdx.x) >> 6;
    int lane = threadIdx.x & 63;
    if (wid >= N_NODES) return;
    float di = dinv[wid];
    float2 v0 = *reinterpret_cast<const float2*>(&A[(long long)wid * 128 + lane * 2]);
    float sc = di * di;
    float ax = v0.x * sc, ay = v0.y * sc;
    int d = deg[wid]; if (d > PAD) d = PAD;
    const int* e = csr + wid * PAD;
    for (int j = 0; j < d; ++j) {
        int s = e[j];
        float c = di * dinv[s];
        float2 v = *reinterpret_cast<const float2*>(&A[(long long)s * 128 + lane * 2]);
        ax += v.x * c; ay += v.y * c;
    }
    *reinterpret_cast<float2*>(&out[(long long)wid * 128 + lane * 2]) = make_float2(ax, ay);
}

// ---------------- fused layer-3 gather + mean-pool + MLP head ----------------
// One block (4 waves) per graph. batch is SORTED -> binary-search node range.

__global__ __launch_bounds__(256) void pool_head_k(
        const float* __restrict__ A,      // layer-3 GEMM output [N,128]
        const int* __restrict__ csr, const int* __restrict__ deg,
        const float* __restrict__ dinv, const float* __restrict__ b3,
        const int* __restrict__ batch,
        const float* __restrict__ fw1, const float* __restrict__ fb1,
        const float* __restrict__ fw2, const float* __restrict__ fb2,
        float* __restrict__ out) {
    __shared__ float part[4][HID];
    __shared__ float ps[HID];
    const int g = blockIdx.x;
    const int w = threadIdx.x >> 6, lane = threadIdx.x & 63;

    // lower_bound(batch, g) and lower_bound(batch, g+1)
    int start, end;
    {
        int l = 0, h = N_NODES;
        while (l < h) { int m = (l + h) >> 1; if (batch[m] < g) l = m + 1; else h = m; }
        start = l;
        h = N_NODES;
        while (l < h) { int m = (l + h) >> 1; if (batch[m] < g + 1) l = m + 1; else h = m; }
        end = l;
    }

    float sx = 0.f, sy = 0.f;
    const float bx = b3[lane * 2], by = b3[lane * 2 + 1];
    for (int i = start + w; i < end; i += 4) {
        float di = dinv[i];
        float2 v0 = *reinterpret_cast<const float2*>(&A[(long long)i * 128 + lane * 2]);
        float sc = di * di;
        float ax = v0.x * sc, ay = v0.y * sc;
        int d = deg[i]; if (d > PAD) d = PAD;
        const int* e = csr + i * PAD;
        for (int j = 0; j < d; ++j) {
            int s = e[j];
            float c = di * dinv[s];
            float2 v = *reinterpret_cast<const float2*>(&A[(long long)s * 128 + lane * 2]);
            ax += v.x * c; ay += v.y * c;
        }
        sx += fmaxf(ax + bx, 0.f);
        sy += fmaxf(ay + by, 0.f);
    }
    part[w][lane * 2] = sx;
    part[w][lane * 2 + 1] = sy;
    __syncthreads();

    if (w == 0) {
        float inv = (end > start) ? 1.0f / (float)(end - start) : 0.0f;
        ps[lane * 2]     = (part[0][lane * 2]     + part[1][lane * 2]     + part[2][lane * 2]     + part[3][lane * 2])     * inv;
        ps[lane * 2 + 1] = (part[0][lane * 2 + 1] + part[1][lane * 2 + 1] + part[2][lane * 2 + 1] + part[3][lane * 2 + 1]) * inv;
    }
    __syncthreads();

    if (w == 0) {
        float acc = fb1[lane];
        #pragma unroll 8
        for (int k = 0; k < HID; ++k) acc = fmaf(ps[k], fw1[k * 64 + lane], acc);
        float v = fmaxf(acc, 0.0f) * fw2[lane];
        #pragma unroll
        for (int off = 32; off > 0; off >>= 1) v += __shfl_down(v, off);
        if (lane == 0) out[g] = v + fb2[0];
    }
}

// ---------------- launch ----------------

extern "C" void kernel_launch(void* const* d_in, const int* in_sizes, int n_in,
                              void* d_out, int out_size, void* d_ws, size_t ws_size,
                              hipStream_t stream) {
    const float* x     = (const float*)d_in[0];
    const int*   ei    = (const int*)d_in[1];
    const int*   batch = (const int*)d_in[2];
    const float* W1 = (const float*)d_in[3];
    const float* b1 = (const float*)d_in[4];
    const float* W2 = (const float*)d_in[5];
    const float* b2 = (const float*)d_in[6];
    const float* W3 = (const float*)d_in[7];
    const float* b3 = (const float*)d_in[8];
    const float* fw1 = (const float*)d_in[9];
    const float* fb1 = (const float*)d_in[10];
    const float* fw2 = (const float*)d_in[11];
    const float* fb2 = (const float*)d_in[12];
    float* out = (float*)d_out;

    const int* src = ei;
    const int* dst = ei + N_EDGES;

    // workspace layout
    char* p = (char*)d_ws;
    float* dinv = (float*)p;  p += 100352 * 4;
    int*   cur  = (int*)p;    p += 100352 * 4;
    int*   csr  = (int*)p;    p += (size_t)N_NODES * PAD * 4;
    ushort* wth = (ushort*)p; p += 256 * 256 * 2;
    ushort* wtl = (ushort*)p; p += 256 * 256 * 2;
    float* bufW = (float*)p;                              // 100000*256 floats
    float* xpad = bufW;                                   // aliases: 100000*80
    float* bufA = (float*)(p + (size_t)N_NODES * 80 * 4); // aliases: 100000*128
    p += (size_t)N_NODES * 256 * 4;
    float* bufB = (float*)p;  p += (size_t)N_NODES * 128 * 4;

    const int T = 256;
    const int gw = (N_NODES * 64 + T - 1) / T;  // one wave per node

    // CSR + dinv
    zero_int_k<<<(N_NODES + T - 1) / T, T, 0, stream>>>(cur, N_NODES);
    fill_csr_k<<<(N_EDGES + T - 1) / T, T, 0, stream>>>(src, dst, cur, csr);
    dinv_k<<<(N_NODES + T - 1) / T, T, 0, stream>>>(cur, dinv, N_NODES);

    // layer 1: gather-first on 78 feats, then GEMM (K=80 padded) with bias+relu
    gather78_k<<<gw, T, 0, stream>>>(x, csr, cur, dinv, xpad);
    prep_wt_k<<<(128 * 256 + T - 1) / T, T, 0, stream>>>(W1, wth, wtl, NODE_F, 128);
    gemm_mfma_k<true><<<dim3(782, 1), 256, 0, stream>>>(xpad, 80, 80, N_NODES, wth, wtl, b1, bufA, 128);

    // layer 2: gather-first on 128 feats, then GEMM 128->256 with bias+relu
    gather128_k<<<gw, T, 0, stream>>>(bufA, csr, cur, dinv, bufB);
    prep_wt_k<<<(256 * 256 + T - 1) / T, T, 0, stream>>>(W2, wth, wtl, HID, 256);
    gemm_mfma_k<true><<<dim3(782, 2), 256, 0, stream>>>(bufB, 128, 128, N_NODES, wth, wtl, b2, bufW, 256);

    // layer 3: GEMM 256->128 plain; gather+bias+relu+pool+head fused
    prep_wt_k<<<(128 * 256 + T - 1) / T, T, 0, stream>>>(W3, wth, wtl, 2 * HID, 128);
    gemm_mfma_k<false><<<dim3(782, 1), 256, 0, stream>>>(bufW, 256, 256, N_NODES, wth, wtl, nullptr, bufB, 128);

    pool_head_k<<<N_GRAPHS, 256, 0, stream>>>(bufB, csr, cur, dinv, b3, batch,
                                              fw1, fb1, fw2, fb2, out);
}

// Round 5
// 387.874 us; speedup vs baseline: 3.6115x; 1.1715x over previous
//
#include <hip/hip_runtime.h>

#define N_NODES 100000
#define N_EDGES 400000
#define N_GRAPHS 2000
#define NODE_F 78
#define HID 128
#define PAD 32

typedef __attribute__((ext_vector_type(8))) short short8v;
typedef __attribute__((ext_vector_type(4))) float f32x4;

__device__ __forceinline__ ushort f2bf(float f) {
    unsigned u = __float_as_uint(f);
    unsigned r = (u + 0x7FFFu + ((u >> 16) & 1u)) >> 16;  // round-to-nearest-even
    return (ushort)r;
}
__device__ __forceinline__ float bf2f(ushort b) {
    return __uint_as_float(((unsigned)b) << 16);
}

// ---------------- CSR build ----------------

__global__ void zero_int_k(int* __restrict__ p, int n) {
    int i = blockIdx.x * blockDim.x + threadIdx.x;
    if (i < n) p[i] = 0;
}

__global__ void fill_csr_k(const int* __restrict__ src, const int* __restrict__ dst,
                           int* __restrict__ cursor, int* __restrict__ csr) {
    int e = blockIdx.x * blockDim.x + threadIdx.x;
    if (e >= N_EDGES) return;
    int s = src[e], d = dst[e];
    int p = atomicAdd(&cursor[d], 1);
    if (p < PAD) csr[d * PAD + p] = s;
}

__global__ void dinv_k(const int* __restrict__ deg, float* __restrict__ dinv, int n) {
    int i = blockIdx.x * blockDim.x + threadIdx.x;
    if (i < n) dinv[i] = rsqrtf((float)deg[i] + 1.0f);
}

// ---------------- weight prep: W[K][N] fp32 -> Wt hi/lo bf16 [N][256], zero-padded ----------------

__global__ void prep_wt_k(const float* __restrict__ W, ushort* __restrict__ Wth,
                          ushort* __restrict__ Wtl, int K, int N) {
    int idx = blockIdx.x * blockDim.x + threadIdx.x;
    if (idx >= N * 256) return;
    int n = idx >> 8, k = idx & 255;
    float v = (k < K) ? W[(long long)k * N + n] : 0.0f;
    ushort h = f2bf(v);
    ushort l = f2bf(v - bf2f(h));
    Wth[n * 256 + k] = h;
    Wtl[n * 256 + k] = l;
}

// ---------------- split-bf16 MFMA GEMM (layer 1): C = A @ W, + bias + relu ----------------
// BM=128, BN=128, BK=64. 256 threads = 4 waves.

__global__ __launch_bounds__(256) void gemm_mfma_k(
        const float* __restrict__ A, int lda, int K, int M,
        const ushort* __restrict__ Wth, const ushort* __restrict__ Wtl,
        const float* __restrict__ bias, float* __restrict__ C, int N) {
    __shared__ ushort Ah[128 * 64];
    __shared__ ushort Al[128 * 64];
    __shared__ ushort Bh[128 * 64];
    __shared__ ushort Bl[128 * 64];
    const int tid = threadIdx.x;
    const int w = tid >> 6, l = tid & 63;
    const int bm = blockIdx.x * 128;
    const int bn = blockIdx.y * 128;

    f32x4 acc[2][8];
    #pragma unroll
    for (int m = 0; m < 2; ++m)
        #pragma unroll
        for (int j = 0; j < 8; ++j)
            acc[m][j] = (f32x4){0.f, 0.f, 0.f, 0.f};

    for (int k0 = 0; k0 < K; k0 += 64) {
        __syncthreads();
        #pragma unroll
        for (int i = 0; i < 8; ++i) {
            int idx = tid + i * 256;
            int r = idx >> 4;
            int kq = (idx & 15) * 4;
            ushort4 h4, l4;
            if (k0 + kq < K) {
                int gr = bm + r; if (gr >= M) gr = M - 1;
                float4 v = *reinterpret_cast<const float4*>(&A[(long long)gr * lda + k0 + kq]);
                h4.x = f2bf(v.x); l4.x = f2bf(v.x - bf2f(h4.x));
                h4.y = f2bf(v.y); l4.y = f2bf(v.y - bf2f(h4.y));
                h4.z = f2bf(v.z); l4.z = f2bf(v.z - bf2f(h4.z));
                h4.w = f2bf(v.w); l4.w = f2bf(v.w - bf2f(h4.w));
            } else {
                h4 = (ushort4){0, 0, 0, 0};
                l4 = (ushort4){0, 0, 0, 0};
            }
            int e = r * 64 + ((kq >> 3) ^ (r & 7)) * 8 + (kq & 7);
            *reinterpret_cast<ushort4*>(&Ah[e]) = h4;
            *reinterpret_cast<ushort4*>(&Al[e]) = l4;
        }
        #pragma unroll
        for (int i = 0; i < 4; ++i) {
            int idx = tid + i * 256;
            int n = idx >> 3, s0 = idx & 7;
            long long g = (long long)(bn + n) * 256 + k0 + s0 * 8;
            short8v vh = *reinterpret_cast<const short8v*>(&Wth[g]);
            short8v vl = *reinterpret_cast<const short8v*>(&Wtl[g]);
            int e = n * 64 + (s0 ^ (n & 7)) * 8;
            *reinterpret_cast<short8v*>(&Bh[e]) = vh;
            *reinterpret_cast<short8v*>(&Bl[e]) = vl;
        }
        __syncthreads();
        #pragma unroll
        for (int ks = 0; ks < 2; ++ks) {
            short8v ah[2], al[2];
            #pragma unroll
            for (int m = 0; m < 2; ++m) {
                int r = w * 32 + m * 16 + (l & 15);
                int e = r * 64 + ((ks * 4 + (l >> 4)) ^ (r & 7)) * 8;
                ah[m] = *reinterpret_cast<const short8v*>(&Ah[e]);
                al[m] = *reinterpret_cast<const short8v*>(&Al[e]);
            }
            #pragma unroll
            for (int j = 0; j < 8; ++j) {
                int n = j * 16 + (l & 15);
                int e = n * 64 + ((ks * 4 + (l >> 4)) ^ (n & 7)) * 8;
                short8v bh = *reinterpret_cast<const short8v*>(&Bh[e]);
                short8v bl = *reinterpret_cast<const short8v*>(&Bl[e]);
                #pragma unroll
                for (int m = 0; m < 2; ++m) {
                    acc[m][j] = __builtin_amdgcn_mfma_f32_16x16x32_bf16(ah[m], bh, acc[m][j], 0, 0, 0);
                    acc[m][j] = __builtin_amdgcn_mfma_f32_16x16x32_bf16(ah[m], bl, acc[m][j], 0, 0, 0);
                    acc[m][j] = __builtin_amdgcn_mfma_f32_16x16x32_bf16(al[m], bh, acc[m][j], 0, 0, 0);
                }
            }
        }
    }

    #pragma unroll
    for (int j = 0; j < 8; ++j) {
        int gc = bn + j * 16 + (l & 15);
        float bv = bias[gc];
        #pragma unroll
        for (int m = 0; m < 2; ++m) {
            #pragma unroll
            for (int rg = 0; rg < 4; ++rg) {
                int gr = bm + w * 32 + m * 16 + (l >> 4) * 4 + rg;
                if (gr < M)
                    C[(long long)gr * N + gc] = fmaxf(acc[m][j][rg] + bv, 0.0f);
            }
        }
    }
}

// ---------------- fused layer2+layer3 GEMM: C3 = relu(A@W2 + b2) @ W3 ----------------
// BM=64, 256 threads = 4 waves; wave w owns rows w*16..w*16+15.
// Phase 1: acc2[16] = A[64x128] @ W2[128x256]; phase 2: per 64-col chunk of T,
// convert relu(acc2+b2) to bf16 hi/lo through LDS, multiply by W3[256x128].

__global__ __launch_bounds__(256) void gemm23_k(
        const float* __restrict__ A,   // [M,128]
        const ushort* __restrict__ W2h, const ushort* __restrict__ W2l,  // [256][256]
        const float* __restrict__ b2,
        const ushort* __restrict__ W3h, const ushort* __restrict__ W3l,  // [128][256]
        float* __restrict__ C, int M) {
    __shared__ ushort Ah[64 * 64];
    __shared__ ushort Al[64 * 64];
    __shared__ ushort Bh[128 * 64];
    __shared__ ushort Bl[128 * 64];
    const int tid = threadIdx.x;
    const int w = tid >> 6, l = tid & 63;
    const int bm = blockIdx.x * 64;

    f32x4 acc2[16];
    #pragma unroll
    for (int j = 0; j < 16; ++j) acc2[j] = (f32x4){0.f, 0.f, 0.f, 0.f};

    // ---- phase 1: T = A @ W2 (K=128) ----
    for (int k0 = 0; k0 < 128; k0 += 64) {
        __syncthreads();
        // stage A tile 64x64 fp32 -> hi/lo
        #pragma unroll
        for (int i = 0; i < 4; ++i) {
            int idx = tid + i * 256;
            int r = idx >> 4;
            int kq = (idx & 15) * 4;
            int gr = bm + r; if (gr >= M) gr = M - 1;
            float4 v = *reinterpret_cast<const float4*>(&A[(long long)gr * 128 + k0 + kq]);
            ushort4 h4, l4;
            h4.x = f2bf(v.x); l4.x = f2bf(v.x - bf2f(h4.x));
            h4.y = f2bf(v.y); l4.y = f2bf(v.y - bf2f(h4.y));
            h4.z = f2bf(v.z); l4.z = f2bf(v.z - bf2f(h4.z));
            h4.w = f2bf(v.w); l4.w = f2bf(v.w - bf2f(h4.w));
            int e = r * 64 + ((kq >> 3) ^ (r & 7)) * 8 + (kq & 7);
            *reinterpret_cast<ushort4*>(&Ah[e]) = h4;
            *reinterpret_cast<ushort4*>(&Al[e]) = l4;
        }
        #pragma unroll
        for (int nh = 0; nh < 2; ++nh) {
            if (nh) __syncthreads();
            // stage W2 tile [128n x 64k]
            #pragma unroll
            for (int i = 0; i < 4; ++i) {
                int idx = tid + i * 256;
                int n = idx >> 3, s0 = idx & 7;
                long long g = (long long)(nh * 128 + n) * 256 + k0 + s0 * 8;
                short8v vh = *reinterpret_cast<const short8v*>(&W2h[g]);
                short8v vl = *reinterpret_cast<const short8v*>(&W2l[g]);
                int e = n * 64 + (s0 ^ (n & 7)) * 8;
                *reinterpret_cast<short8v*>(&Bh[e]) = vh;
                *reinterpret_cast<short8v*>(&Bl[e]) = vl;
            }
            __syncthreads();
            #pragma unroll
            for (int ks = 0; ks < 2; ++ks) {
                int r = w * 16 + (l & 15);
                int ea = r * 64 + ((ks * 4 + (l >> 4)) ^ (r & 7)) * 8;
                short8v ah = *reinterpret_cast<const short8v*>(&Ah[ea]);
                short8v al = *reinterpret_cast<const short8v*>(&Al[ea]);
                #pragma unroll
                for (int jl = 0; jl < 8; ++jl) {
                    int n = jl * 16 + (l & 15);
                    int e = n * 64 + ((ks * 4 + (l >> 4)) ^ (n & 7)) * 8;
                    short8v bh = *reinterpret_cast<const short8v*>(&Bh[e]);
                    short8v bl = *reinterpret_cast<const short8v*>(&Bl[e]);
                    int j = nh * 8 + jl;
                    acc2[j] = __builtin_amdgcn_mfma_f32_16x16x32_bf16(ah, bh, acc2[j], 0, 0, 0);
                    acc2[j] = __builtin_amdgcn_mfma_f32_16x16x32_bf16(ah, bl, acc2[j], 0, 0, 0);
                    acc2[j] = __builtin_amdgcn_mfma_f32_16x16x32_bf16(al, bh, acc2[j], 0, 0, 0);
                }
            }
        }
    }

    // ---- phase 2: C3 = relu(T + b2) @ W3, K=256 in 4 chunks of 64 ----
    f32x4 acc3[8];
    #pragma unroll
    for (int j = 0; j < 8; ++j) acc3[j] = (f32x4){0.f, 0.f, 0.f, 0.f};

    #pragma unroll
    for (int ch = 0; ch < 4; ++ch) {
        __syncthreads();  // previous chunk (or phase-1) LDS reads complete
        // write T chunk (cols ch*64..+64) as bf16 hi/lo into Ah/Al
        #pragma unroll
        for (int jj = 0; jj < 4; ++jj) {
            int j = ch * 4 + jj;
            float bv = b2[j * 16 + (l & 15)];
            #pragma unroll
            for (int rg = 0; rg < 4; ++rg) {
                int r = w * 16 + (l >> 4) * 4 + rg;
                float v = fmaxf(acc2[j][rg] + bv, 0.f);
                ushort h = f2bf(v);
                ushort lo = f2bf(v - bf2f(h));
                int cl = jj * 16 + (l & 15);
                int e = r * 64 + ((cl >> 3) ^ (r & 7)) * 8 + (cl & 7);
                Ah[e] = h; Al[e] = lo;
            }
        }
        // stage W3 tile [128n x 64k], k-offset ch*64
        #pragma unroll
        for (int i = 0; i < 4; ++i) {
            int idx = tid + i * 256;
            int n = idx >> 3, s0 = idx & 7;
            long long g = (long long)n * 256 + ch * 64 + s0 * 8;
            short8v vh = *reinterpret_cast<const short8v*>(&W3h[g]);
            short8v vl = *reinterpret_cast<const short8v*>(&W3l[g]);
            int e = n * 64 + (s0 ^ (n & 7)) * 8;
            *reinterpret_cast<short8v*>(&Bh[e]) = vh;
            *reinterpret_cast<short8v*>(&Bl[e]) = vl;
        }
        __syncthreads();
        #pragma unroll
        for (int ks = 0; ks < 2; ++ks) {
            int r = w * 16 + (l & 15);
            int ea = r * 64 + ((ks * 4 + (l >> 4)) ^ (r & 7)) * 8;
            short8v ah = *reinterpret_cast<const short8v*>(&Ah[ea]);
            short8v al = *reinterpret_cast<const short8v*>(&Al[ea]);
            #pragma unroll
            for (int j3 = 0; j3 < 8; ++j3) {
                int n = j3 * 16 + (l & 15);
                int e = n * 64 + ((ks * 4 + (l >> 4)) ^ (n & 7)) * 8;
                short8v bh = *reinterpret_cast<const short8v*>(&Bh[e]);
                short8v bl = *reinterpret_cast<const short8v*>(&Bl[e]);
                acc3[j3] = __builtin_amdgcn_mfma_f32_16x16x32_bf16(ah, bh, acc3[j3], 0, 0, 0);
                acc3[j3] = __builtin_amdgcn_mfma_f32_16x16x32_bf16(ah, bl, acc3[j3], 0, 0, 0);
                acc3[j3] = __builtin_amdgcn_mfma_f32_16x16x32_bf16(al, bh, acc3[j3], 0, 0, 0);
            }
        }
    }

    // ---- epilogue: C3 (no bias) ----
    #pragma unroll
    for (int j = 0; j < 8; ++j) {
        int gc = j * 16 + (l & 15);
        #pragma unroll
        for (int rg = 0; rg < 4; ++rg) {
            int gr = bm + w * 16 + (l >> 4) * 4 + rg;
            if (gr < M) C[(long long)gr * 128 + gc] = acc3[j][rg];
        }
    }
}

// ---------------- gathers (edge-batched int4) ----------------

// aggregate raw x [N,78] -> out [N,80] (cols 78,79 = 0)
__global__ __launch_bounds__(256) void gather78_k(const float* __restrict__ X,
        const int* __restrict__ csr, const int* __restrict__ deg,
        const float* __restrict__ dinv, float* __restrict__ out) {
    int wid = (blockIdx.x * blockDim.x + threadIdx.x) >> 6;
    int lane = threadIdx.x & 63;
    if (wid >= N_NODES) return;
    float di = dinv[wid];
    float ax = 0.f, ay = 0.f;
    bool act = lane < 39;
    if (act) {
        float2 v = *reinterpret_cast<const float2*>(&X[(long long)wid * 78 + lane * 2]);
        float sc = di * di;
        ax = v.x * sc; ay = v.y * sc;
    }
    int d = deg[wid]; if (d > PAD) d = PAD;
    const int4* e4 = reinterpret_cast<const int4*>(csr + wid * PAD);
    for (int j0 = 0; j0 < d; j0 += 4) {
        int4 e = e4[j0 >> 2];
        int rem = d - j0;
        int s1 = (rem > 1) ? e.y : e.x;
        int s2 = (rem > 2) ? e.z : e.x;
        int s3 = (rem > 3) ? e.w : e.x;
        float c0 = di * dinv[e.x];
        float c1 = (rem > 1) ? di * dinv[s1] : 0.f;
        float c2 = (rem > 2) ? di * dinv[s2] : 0.f;
        float c3 = (rem > 3) ? di * dinv[s3] : 0.f;
        if (act) {
            float2 v0 = *reinterpret_cast<const float2*>(&X[(long long)e.x * 78 + lane * 2]);
            float2 v1 = *reinterpret_cast<const float2*>(&X[(long long)s1  * 78 + lane * 2]);
            float2 v2 = *reinterpret_cast<const float2*>(&X[(long long)s2  * 78 + lane * 2]);
            float2 v3 = *reinterpret_cast<const float2*>(&X[(long long)s3  * 78 + lane * 2]);
            ax += v0.x * c0 + v1.x * c1 + v2.x * c2 + v3.x * c3;
            ay += v0.y * c0 + v1.y * c1 + v2.y * c2 + v3.y * c3;
        }
    }
    if (lane < 40)
        *reinterpret_cast<float2*>(&out[(long long)wid * 80 + lane * 2]) = make_float2(ax, ay);
}

// aggregate [N,128] -> [N,128], no bias/relu
__global__ __launch_bounds__(256) void gather128_k(const float* __restrict__ A,
        const int* __restrict__ csr, const int* __restrict__ deg,
        const float* __restrict__ dinv, float* __restrict__ out) {
    int wid = (blockIdx.x * blockDim.x + threadIdx.x) >> 6;
    int lane = threadIdx.x & 63;
    if (wid >= N_NODES) return;
    float di = dinv[wid];
    float2 v0 = *reinterpret_cast<const float2*>(&A[(long long)wid * 128 + lane * 2]);
    float sc = di * di;
    float ax = v0.x * sc, ay = v0.y * sc;
    int d = deg[wid]; if (d > PAD) d = PAD;
    const int4* e4 = reinterpret_cast<const int4*>(csr + wid * PAD);
    for (int j0 = 0; j0 < d; j0 += 4) {
        int4 e = e4[j0 >> 2];
        int rem = d - j0;
        int s1 = (rem > 1) ? e.y : e.x;
        int s2 = (rem > 2) ? e.z : e.x;
        int s3 = (rem > 3) ? e.w : e.x;
        float c0 = di * dinv[e.x];
        float c1 = (rem > 1) ? di * dinv[s1] : 0.f;
        float c2 = (rem > 2) ? di * dinv[s2] : 0.f;
        float c3 = (rem > 3) ? di * dinv[s3] : 0.f;
        float2 w0 = *reinterpret_cast<const float2*>(&A[(long long)e.x * 128 + lane * 2]);
        float2 w1 = *reinterpret_cast<const float2*>(&A[(long long)s1  * 128 + lane * 2]);
        float2 w2 = *reinterpret_cast<const float2*>(&A[(long long)s2  * 128 + lane * 2]);
        float2 w3 = *reinterpret_cast<const float2*>(&A[(long long)s3  * 128 + lane * 2]);
        ax += w0.x * c0 + w1.x * c1 + w2.x * c2 + w3.x * c3;
        ay += w0.y * c0 + w1.y * c1 + w2.y * c2 + w3.y * c3;
    }
    *reinterpret_cast<float2*>(&out[(long long)wid * 128 + lane * 2]) = make_float2(ax, ay);
}

// ---------------- fused layer-3 gather + mean-pool + MLP head ----------------

__global__ __launch_bounds__(256) void pool_head_k(
        const float* __restrict__ A,      // layer-3 GEMM output [N,128]
        const int* __restrict__ csr, const int* __restrict__ deg,
        const float* __restrict__ dinv, const float* __restrict__ b3,
        const int* __restrict__ batch,
        const float* __restrict__ fw1, const float* __restrict__ fb1,
        const float* __restrict__ fw2, const float* __restrict__ fb2,
        float* __restrict__ out) {
    __shared__ float part[4][HID];
    __shared__ float ps[HID];
    const int g = blockIdx.x;
    const int w = threadIdx.x >> 6, lane = threadIdx.x & 63;

    int start, end;
    {
        int l = 0, h = N_NODES;
        while (l < h) { int m = (l + h) >> 1; if (batch[m] < g) l = m + 1; else h = m; }
        start = l;
        h = N_NODES;
        while (l < h) { int m = (l + h) >> 1; if (batch[m] < g + 1) l = m + 1; else h = m; }
        end = l;
    }

    float sx = 0.f, sy = 0.f;
    const float bx = b3[lane * 2], by = b3[lane * 2 + 1];
    for (int i = start + w; i < end; i += 4) {
        float di = dinv[i];
        float2 v0 = *reinterpret_cast<const float2*>(&A[(long long)i * 128 + lane * 2]);
        float sc = di * di;
        float ax = v0.x * sc, ay = v0.y * sc;
        int d = deg[i]; if (d > PAD) d = PAD;
        const int4* e4 = reinterpret_cast<const int4*>(csr + i * PAD);
        for (int j0 = 0; j0 < d; j0 += 4) {
            int4 e = e4[j0 >> 2];
            int rem = d - j0;
            int s1 = (rem > 1) ? e.y : e.x;
            int s2 = (rem > 2) ? e.z : e.x;
            int s3 = (rem > 3) ? e.w : e.x;
            float c0 = di * dinv[e.x];
            float c1 = (rem > 1) ? di * dinv[s1] : 0.f;
            float c2 = (rem > 2) ? di * dinv[s2] : 0.f;
            float c3 = (rem > 3) ? di * dinv[s3] : 0.f;
            float2 w0 = *reinterpret_cast<const float2*>(&A[(long long)e.x * 128 + lane * 2]);
            float2 w1 = *reinterpret_cast<const float2*>(&A[(long long)s1  * 128 + lane * 2]);
            float2 w2 = *reinterpret_cast<const float2*>(&A[(long long)s2  * 128 + lane * 2]);
            float2 w3 = *reinterpret_cast<const float2*>(&A[(long long)s3  * 128 + lane * 2]);
            ax += w0.x * c0 + w1.x * c1 + w2.x * c2 + w3.x * c3;
            ay += w0.y * c0 + w1.y * c1 + w2.y * c2 + w3.y * c3;
        }
        sx += fmaxf(ax + bx, 0.f);
        sy += fmaxf(ay + by, 0.f);
    }
    part[w][lane * 2] = sx;
    part[w][lane * 2 + 1] = sy;
    __syncthreads();

    if (w == 0) {
        float inv = (end > start) ? 1.0f / (float)(end - start) : 0.0f;
        ps[lane * 2]     = (part[0][lane * 2]     + part[1][lane * 2]     + part[2][lane * 2]     + part[3][lane * 2])     * inv;
        ps[lane * 2 + 1] = (part[0][lane * 2 + 1] + part[1][lane * 2 + 1] + part[2][lane * 2 + 1] + part[3][lane * 2 + 1]) * inv;
    }
    __syncthreads();

    if (w == 0) {
        float acc = fb1[lane];
        #pragma unroll 8
        for (int k = 0; k < HID; ++k) acc = fmaf(ps[k], fw1[k * 64 + lane], acc);
        float v = fmaxf(acc, 0.0f) * fw2[lane];
        #pragma unroll
        for (int off = 32; off > 0; off >>= 1) v += __shfl_down(v, off);
        if (lane == 0) out[g] = v + fb2[0];
    }
}

// ---------------- launch ----------------

extern "C" void kernel_launch(void* const* d_in, const int* in_sizes, int n_in,
                              void* d_out, int out_size, void* d_ws, size_t ws_size,
                              hipStream_t stream) {
    const float* x     = (const float*)d_in[0];
    const int*   ei    = (const int*)d_in[1];
    const int*   batch = (const int*)d_in[2];
    const float* W1 = (const float*)d_in[3];
    const float* b1 = (const float*)d_in[4];
    const float* W2 = (const float*)d_in[5];
    const float* b2 = (const float*)d_in[6];
    const float* W3 = (const float*)d_in[7];
    const float* b3 = (const float*)d_in[8];
    const float* fw1 = (const float*)d_in[9];
    const float* fb1 = (const float*)d_in[10];
    const float* fw2 = (const float*)d_in[11];
    const float* fb2 = (const float*)d_in[12];
    float* out = (float*)d_out;

    const int* src = ei;
    const int* dst = ei + N_EDGES;

    // workspace layout (~200 MB; round-2 proved ws_size >= 219 MB)
    char* p = (char*)d_ws;
    float* dinv = (float*)p;  p += 100352 * 4;
    int*   cur  = (int*)p;    p += 100352 * 4;
    int*   csr  = (int*)p;    p += (size_t)N_NODES * PAD * 4;
    ushort* w2h = (ushort*)p; p += 256 * 256 * 2;
    ushort* w2l = (ushort*)p; p += 256 * 256 * 2;
    ushort* w3h = (ushort*)p; p += 256 * 256 * 2;
    ushort* w3l = (ushort*)p; p += 256 * 256 * 2;
    float* xpad = (float*)p;  p += (size_t)N_NODES * 80 * 4;
    float* buf1 = (float*)p;  p += (size_t)N_NODES * 128 * 4;
    float* buf2 = (float*)p;  p += (size_t)N_NODES * 128 * 4;
    float* buf3 = (float*)p;  p += (size_t)N_NODES * 128 * 4;

    const int T = 256;
    const int gw = (N_NODES * 64 + T - 1) / T;  // one wave per node

    // CSR + dinv
    zero_int_k<<<(N_NODES + T - 1) / T, T, 0, stream>>>(cur, N_NODES);
    fill_csr_k<<<(N_EDGES + T - 1) / T, T, 0, stream>>>(src, dst, cur, csr);
    dinv_k<<<(N_NODES + T - 1) / T, T, 0, stream>>>(cur, dinv, N_NODES);

    // layer 1: gather-first on 78 feats, GEMM (K=80 padded) + bias + relu
    gather78_k<<<gw, T, 0, stream>>>(x, csr, cur, dinv, xpad);
    prep_wt_k<<<(128 * 256 + T - 1) / T, T, 0, stream>>>(W1, w2h, w2l, NODE_F, 128);
    gemm_mfma_k<<<dim3(782, 1), 256, 0, stream>>>(xpad, 80, 80, N_NODES, w2h, w2l, b1, buf1, 128);

    // layer 2 gather, then fused L2+L3 GEMM
    gather128_k<<<gw, T, 0, stream>>>(buf1, csr, cur, dinv, buf2);
    prep_wt_k<<<(256 * 256 + T - 1) / T, T, 0, stream>>>(W2, w2h, w2l, HID, 256);
    prep_wt_k<<<(128 * 256 + T - 1) / T, T, 0, stream>>>(W3, w3h, w3l, 2 * HID, 128);
    gemm23_k<<<1563, 256, 0, stream>>>(buf2, w2h, w2l, b2, w3h, w3l, buf3, N_NODES);

    // layer-3 gather + bias + relu + mean-pool + MLP head
    pool_head_k<<<N_GRAPHS, 256, 0, stream>>>(buf3, csr, cur, dinv, b3, batch,
                                              fw1, fb1, fw2, fb2, out);
}

// Round 6
// 369.920 us; speedup vs baseline: 3.7867x; 1.0485x over previous
//
#include <hip/hip_runtime.h>

#define N_NODES 100000
#define N_EDGES 400000
#define N_GRAPHS 2000
#define NODE_F 78
#define HID 128
#define PAD 32

typedef __attribute__((ext_vector_type(8))) short short8v;
typedef __attribute__((ext_vector_type(4))) float f32x4;

__device__ __forceinline__ ushort f2bf(float f) {
    unsigned u = __float_as_uint(f);
    unsigned r = (u + 0x7FFFu + ((u >> 16) & 1u)) >> 16;  // round-to-nearest-even
    return (ushort)r;
}
__device__ __forceinline__ float bf2f(ushort b) {
    return __uint_as_float(((unsigned)b) << 16);
}
// load 2 consecutive bf16 as floats (one 4B load)
__device__ __forceinline__ float2 bfx2(const ushort* p) {
    unsigned u = *reinterpret_cast<const unsigned*>(p);
    return make_float2(__uint_as_float(u << 16), __uint_as_float(u & 0xffff0000u));
}

// ---------------- CSR build ----------------

__global__ void zero_int_k(int* __restrict__ p, int n) {
    int i = blockIdx.x * blockDim.x + threadIdx.x;
    if (i < n) p[i] = 0;
}

__global__ void fill_csr_k(const int* __restrict__ src, const int* __restrict__ dst,
                           int* __restrict__ cursor, int* __restrict__ csr) {
    int e = blockIdx.x * blockDim.x + threadIdx.x;
    if (e >= N_EDGES) return;
    int s = src[e], d = dst[e];
    int p = atomicAdd(&cursor[d], 1);
    if (p < PAD) csr[d * PAD + p] = s;
}

__global__ void dinv_k(const int* __restrict__ deg, float* __restrict__ dinv, int n) {
    int i = blockIdx.x * blockDim.x + threadIdx.x;
    if (i < n) dinv[i] = rsqrtf((float)deg[i] + 1.0f);
}

// ---------------- x -> bf16, padded to 80 cols ----------------

__global__ void x2bf_k(const float* __restrict__ x, ushort* __restrict__ xb) {
    int idx = blockIdx.x * blockDim.x + threadIdx.x;
    if (idx >= N_NODES * 80) return;
    int n = idx / 80, f = idx - n * 80;
    xb[idx] = (f < NODE_F) ? f2bf(x[(long long)n * NODE_F + f]) : (ushort)0;
}

// ---------------- weight prep: W[K][N] fp32 -> Wt hi/lo bf16 [N][256], zero-padded ----------------

__global__ void prep_wt_k(const float* __restrict__ W, ushort* __restrict__ Wth,
                          ushort* __restrict__ Wtl, int K, int N) {
    int idx = blockIdx.x * blockDim.x + threadIdx.x;
    if (idx >= N * 256) return;
    int n = idx >> 8, k = idx & 255;
    float v = (k < K) ? W[(long long)k * N + n] : 0.0f;
    ushort h = f2bf(v);
    ushort l = f2bf(v - bf2f(h));
    Wth[n * 256 + k] = h;
    Wtl[n * 256 + k] = l;
}

// ---------------- split-bf16 MFMA GEMM (layer 1): C_bf16 = relu(A @ W + bias) ----------------
// BM=128, BN=128, BK=64. 256 threads = 4 waves.

__global__ __launch_bounds__(256) void gemm_mfma_k(
        const float* __restrict__ A, int lda, int K, int M,
        const ushort* __restrict__ Wth, const ushort* __restrict__ Wtl,
        const float* __restrict__ bias, ushort* __restrict__ C, int N) {
    __shared__ ushort Ah[128 * 64];
    __shared__ ushort Al[128 * 64];
    __shared__ ushort Bh[128 * 64];
    __shared__ ushort Bl[128 * 64];
    const int tid = threadIdx.x;
    const int w = tid >> 6, l = tid & 63;
    const int bm = blockIdx.x * 128;
    const int bn = blockIdx.y * 128;

    f32x4 acc[2][8];
    #pragma unroll
    for (int m = 0; m < 2; ++m)
        #pragma unroll
        for (int j = 0; j < 8; ++j)
            acc[m][j] = (f32x4){0.f, 0.f, 0.f, 0.f};

    for (int k0 = 0; k0 < K; k0 += 64) {
        __syncthreads();
        #pragma unroll
        for (int i = 0; i < 8; ++i) {
            int idx = tid + i * 256;
            int r = idx >> 4;
            int kq = (idx & 15) * 4;
            ushort4 h4, l4;
            if (k0 + kq < K) {
                int gr = bm + r; if (gr >= M) gr = M - 1;
                float4 v = *reinterpret_cast<const float4*>(&A[(long long)gr * lda + k0 + kq]);
                h4.x = f2bf(v.x); l4.x = f2bf(v.x - bf2f(h4.x));
                h4.y = f2bf(v.y); l4.y = f2bf(v.y - bf2f(h4.y));
                h4.z = f2bf(v.z); l4.z = f2bf(v.z - bf2f(h4.z));
                h4.w = f2bf(v.w); l4.w = f2bf(v.w - bf2f(h4.w));
            } else {
                h4 = (ushort4){0, 0, 0, 0};
                l4 = (ushort4){0, 0, 0, 0};
            }
            int e = r * 64 + ((kq >> 3) ^ (r & 7)) * 8 + (kq & 7);
            *reinterpret_cast<ushort4*>(&Ah[e]) = h4;
            *reinterpret_cast<ushort4*>(&Al[e]) = l4;
        }
        #pragma unroll
        for (int i = 0; i < 4; ++i) {
            int idx = tid + i * 256;
            int n = idx >> 3, s0 = idx & 7;
            long long g = (long long)(bn + n) * 256 + k0 + s0 * 8;
            short8v vh = *reinterpret_cast<const short8v*>(&Wth[g]);
            short8v vl = *reinterpret_cast<const short8v*>(&Wtl[g]);
            int e = n * 64 + (s0 ^ (n & 7)) * 8;
            *reinterpret_cast<short8v*>(&Bh[e]) = vh;
            *reinterpret_cast<short8v*>(&Bl[e]) = vl;
        }
        __syncthreads();
        #pragma unroll
        for (int ks = 0; ks < 2; ++ks) {
            short8v ah[2], al[2];
            #pragma unroll
            for (int m = 0; m < 2; ++m) {
                int r = w * 32 + m * 16 + (l & 15);
                int e = r * 64 + ((ks * 4 + (l >> 4)) ^ (r & 7)) * 8;
                ah[m] = *reinterpret_cast<const short8v*>(&Ah[e]);
                al[m] = *reinterpret_cast<const short8v*>(&Al[e]);
            }
            #pragma unroll
            for (int j = 0; j < 8; ++j) {
                int n = j * 16 + (l & 15);
                int e = n * 64 + ((ks * 4 + (l >> 4)) ^ (n & 7)) * 8;
                short8v bh = *reinterpret_cast<const short8v*>(&Bh[e]);
                short8v bl = *reinterpret_cast<const short8v*>(&Bl[e]);
                #pragma unroll
                for (int m = 0; m < 2; ++m) {
                    acc[m][j] = __builtin_amdgcn_mfma_f32_16x16x32_bf16(ah[m], bh, acc[m][j], 0, 0, 0);
                    acc[m][j] = __builtin_amdgcn_mfma_f32_16x16x32_bf16(ah[m], bl, acc[m][j], 0, 0, 0);
                    acc[m][j] = __builtin_amdgcn_mfma_f32_16x16x32_bf16(al[m], bh, acc[m][j], 0, 0, 0);
                }
            }
        }
    }

    #pragma unroll
    for (int j = 0; j < 8; ++j) {
        int gc = bn + j * 16 + (l & 15);
        float bv = bias[gc];
        #pragma unroll
        for (int m = 0; m < 2; ++m) {
            #pragma unroll
            for (int rg = 0; rg < 4; ++rg) {
                int gr = bm + w * 32 + m * 16 + (l >> 4) * 4 + rg;
                if (gr < M)
                    C[(long long)gr * N + gc] = f2bf(fmaxf(acc[m][j][rg] + bv, 0.0f));
            }
        }
    }
}

// ---------------- fused layer2+layer3 GEMM: C3_bf16 = relu(A@W2 + b2) @ W3 ----------------
// BM=64, 256 threads = 4 waves; wave w owns rows w*16..w*16+15.

__global__ __launch_bounds__(256) void gemm23_k(
        const float* __restrict__ A,   // [M,128] fp32
        const ushort* __restrict__ W2h, const ushort* __restrict__ W2l,  // [256][256]
        const float* __restrict__ b2,
        const ushort* __restrict__ W3h, const ushort* __restrict__ W3l,  // [128][256]
        ushort* __restrict__ C, int M) {
    __shared__ ushort Ah[64 * 64];
    __shared__ ushort Al[64 * 64];
    __shared__ ushort Bh[128 * 64];
    __shared__ ushort Bl[128 * 64];
    const int tid = threadIdx.x;
    const int w = tid >> 6, l = tid & 63;
    const int bm = blockIdx.x * 64;

    f32x4 acc2[16];
    #pragma unroll
    for (int j = 0; j < 16; ++j) acc2[j] = (f32x4){0.f, 0.f, 0.f, 0.f};

    // ---- phase 1: T = A @ W2 (K=128) ----
    for (int k0 = 0; k0 < 128; k0 += 64) {
        __syncthreads();
        #pragma unroll
        for (int i = 0; i < 4; ++i) {
            int idx = tid + i * 256;
            int r = idx >> 4;
            int kq = (idx & 15) * 4;
            int gr = bm + r; if (gr >= M) gr = M - 1;
            float4 v = *reinterpret_cast<const float4*>(&A[(long long)gr * 128 + k0 + kq]);
            ushort4 h4, l4;
            h4.x = f2bf(v.x); l4.x = f2bf(v.x - bf2f(h4.x));
            h4.y = f2bf(v.y); l4.y = f2bf(v.y - bf2f(h4.y));
            h4.z = f2bf(v.z); l4.z = f2bf(v.z - bf2f(h4.z));
            h4.w = f2bf(v.w); l4.w = f2bf(v.w - bf2f(h4.w));
            int e = r * 64 + ((kq >> 3) ^ (r & 7)) * 8 + (kq & 7);
            *reinterpret_cast<ushort4*>(&Ah[e]) = h4;
            *reinterpret_cast<ushort4*>(&Al[e]) = l4;
        }
        #pragma unroll
        for (int nh = 0; nh < 2; ++nh) {
            if (nh) __syncthreads();
            #pragma unroll
            for (int i = 0; i < 4; ++i) {
                int idx = tid + i * 256;
                int n = idx >> 3, s0 = idx & 7;
                long long g = (long long)(nh * 128 + n) * 256 + k0 + s0 * 8;
                short8v vh = *reinterpret_cast<const short8v*>(&W2h[g]);
                short8v vl = *reinterpret_cast<const short8v*>(&W2l[g]);
                int e = n * 64 + (s0 ^ (n & 7)) * 8;
                *reinterpret_cast<short8v*>(&Bh[e]) = vh;
                *reinterpret_cast<short8v*>(&Bl[e]) = vl;
            }
            __syncthreads();
            #pragma unroll
            for (int ks = 0; ks < 2; ++ks) {
                int r = w * 16 + (l & 15);
                int ea = r * 64 + ((ks * 4 + (l >> 4)) ^ (r & 7)) * 8;
                short8v ah = *reinterpret_cast<const short8v*>(&Ah[ea]);
                short8v al = *reinterpret_cast<const short8v*>(&Al[ea]);
                #pragma unroll
                for (int jl = 0; jl < 8; ++jl) {
                    int n = jl * 16 + (l & 15);
                    int e = n * 64 + ((ks * 4 + (l >> 4)) ^ (n & 7)) * 8;
                    short8v bh = *reinterpret_cast<const short8v*>(&Bh[e]);
                    short8v bl = *reinterpret_cast<const short8v*>(&Bl[e]);
                    int j = nh * 8 + jl;
                    acc2[j] = __builtin_amdgcn_mfma_f32_16x16x32_bf16(ah, bh, acc2[j], 0, 0, 0);
                    acc2[j] = __builtin_amdgcn_mfma_f32_16x16x32_bf16(ah, bl, acc2[j], 0, 0, 0);
                    acc2[j] = __builtin_amdgcn_mfma_f32_16x16x32_bf16(al, bh, acc2[j], 0, 0, 0);
                }
            }
        }
    }

    // ---- phase 2: C3 = relu(T + b2) @ W3, K=256 in 4 chunks of 64 ----
    f32x4 acc3[8];
    #pragma unroll
    for (int j = 0; j < 8; ++j) acc3[j] = (f32x4){0.f, 0.f, 0.f, 0.f};

    #pragma unroll
    for (int ch = 0; ch < 4; ++ch) {
        __syncthreads();
        #pragma unroll
        for (int jj = 0; jj < 4; ++jj) {
            int j = ch * 4 + jj;
            float bv = b2[j * 16 + (l & 15)];
            #pragma unroll
            for (int rg = 0; rg < 4; ++rg) {
                int r = w * 16 + (l >> 4) * 4 + rg;
                float v = fmaxf(acc2[j][rg] + bv, 0.f);
                ushort h = f2bf(v);
                ushort lo = f2bf(v - bf2f(h));
                int cl = jj * 16 + (l & 15);
                int e = r * 64 + ((cl >> 3) ^ (r & 7)) * 8 + (cl & 7);
                Ah[e] = h; Al[e] = lo;
            }
        }
        #pragma unroll
        for (int i = 0; i < 4; ++i) {
            int idx = tid + i * 256;
            int n = idx >> 3, s0 = idx & 7;
            long long g = (long long)n * 256 + ch * 64 + s0 * 8;
            short8v vh = *reinterpret_cast<const short8v*>(&W3h[g]);
            short8v vl = *reinterpret_cast<const short8v*>(&W3l[g]);
            int e = n * 64 + (s0 ^ (n & 7)) * 8;
            *reinterpret_cast<short8v*>(&Bh[e]) = vh;
            *reinterpret_cast<short8v*>(&Bl[e]) = vl;
        }
        __syncthreads();
        #pragma unroll
        for (int ks = 0; ks < 2; ++ks) {
            int r = w * 16 + (l & 15);
            int ea = r * 64 + ((ks * 4 + (l >> 4)) ^ (r & 7)) * 8;
            short8v ah = *reinterpret_cast<const short8v*>(&Ah[ea]);
            short8v al = *reinterpret_cast<const short8v*>(&Al[ea]);
            #pragma unroll
            for (int j3 = 0; j3 < 8; ++j3) {
                int n = j3 * 16 + (l & 15);
                int e = n * 64 + ((ks * 4 + (l >> 4)) ^ (n & 7)) * 8;
                short8v bh = *reinterpret_cast<const short8v*>(&Bh[e]);
                short8v bl = *reinterpret_cast<const short8v*>(&Bl[e]);
                acc3[j3] = __builtin_amdgcn_mfma_f32_16x16x32_bf16(ah, bh, acc3[j3], 0, 0, 0);
                acc3[j3] = __builtin_amdgcn_mfma_f32_16x16x32_bf16(ah, bl, acc3[j3], 0, 0, 0);
                acc3[j3] = __builtin_amdgcn_mfma_f32_16x16x32_bf16(al, bh, acc3[j3], 0, 0, 0);
            }
        }
    }

    #pragma unroll
    for (int j = 0; j < 8; ++j) {
        int gc = j * 16 + (l & 15);
        #pragma unroll
        for (int rg = 0; rg < 4; ++rg) {
            int gr = bm + w * 16 + (l >> 4) * 4 + rg;
            if (gr < M) C[(long long)gr * 128 + gc] = f2bf(acc3[j][rg]);
        }
    }
}

// ---------------- gathers (bf16 rows, edge-batched int4) ----------------

// aggregate xb [N,80] bf16 -> xpad [N,80] fp32
__global__ __launch_bounds__(256) void gather78_k(const ushort* __restrict__ Xb,
        const int* __restrict__ csr, const int* __restrict__ deg,
        const float* __restrict__ dinv, float* __restrict__ out) {
    int wid = (blockIdx.x * blockDim.x + threadIdx.x) >> 6;
    int lane = threadIdx.x & 63;
    if (wid >= N_NODES) return;
    float di = dinv[wid];
    float ax = 0.f, ay = 0.f;
    bool act = lane < 40;
    if (act) {
        float2 v = bfx2(&Xb[(long long)wid * 80 + lane * 2]);
        float sc = di * di;
        ax = v.x * sc; ay = v.y * sc;
    }
    int d = deg[wid]; if (d > PAD) d = PAD;
    const int4* e4 = reinterpret_cast<const int4*>(csr + wid * PAD);
    for (int j0 = 0; j0 < d; j0 += 4) {
        int4 e = e4[j0 >> 2];
        int rem = d - j0;
        int s1 = (rem > 1) ? e.y : e.x;
        int s2 = (rem > 2) ? e.z : e.x;
        int s3 = (rem > 3) ? e.w : e.x;
        float c0 = di * dinv[e.x];
        float c1 = (rem > 1) ? di * dinv[s1] : 0.f;
        float c2 = (rem > 2) ? di * dinv[s2] : 0.f;
        float c3 = (rem > 3) ? di * dinv[s3] : 0.f;
        if (act) {
            float2 v0 = bfx2(&Xb[(long long)e.x * 80 + lane * 2]);
            float2 v1 = bfx2(&Xb[(long long)s1  * 80 + lane * 2]);
            float2 v2 = bfx2(&Xb[(long long)s2  * 80 + lane * 2]);
            float2 v3 = bfx2(&Xb[(long long)s3  * 80 + lane * 2]);
            ax += v0.x * c0 + v1.x * c1 + v2.x * c2 + v3.x * c3;
            ay += v0.y * c0 + v1.y * c1 + v2.y * c2 + v3.y * c3;
        }
    }
    if (act)
        *reinterpret_cast<float2*>(&out[(long long)wid * 80 + lane * 2]) = make_float2(ax, ay);
}

// aggregate buf1 [N,128] bf16 -> buf2 [N,128] fp32
__global__ __launch_bounds__(256) void gather128_k(const ushort* __restrict__ A,
        const int* __restrict__ csr, const int* __restrict__ deg,
        const float* __restrict__ dinv, float* __restrict__ out) {
    int wid = (blockIdx.x * blockDim.x + threadIdx.x) >> 6;
    int lane = threadIdx.x & 63;
    if (wid >= N_NODES) return;
    float di = dinv[wid];
    float2 v0 = bfx2(&A[(long long)wid * 128 + lane * 2]);
    float sc = di * di;
    float ax = v0.x * sc, ay = v0.y * sc;
    int d = deg[wid]; if (d > PAD) d = PAD;
    const int4* e4 = reinterpret_cast<const int4*>(csr + wid * PAD);
    for (int j0 = 0; j0 < d; j0 += 4) {
        int4 e = e4[j0 >> 2];
        int rem = d - j0;
        int s1 = (rem > 1) ? e.y : e.x;
        int s2 = (rem > 2) ? e.z : e.x;
        int s3 = (rem > 3) ? e.w : e.x;
        float c0 = di * dinv[e.x];
        float c1 = (rem > 1) ? di * dinv[s1] : 0.f;
        float c2 = (rem > 2) ? di * dinv[s2] : 0.f;
        float c3 = (rem > 3) ? di * dinv[s3] : 0.f;
        float2 w0 = bfx2(&A[(long long)e.x * 128 + lane * 2]);
        float2 w1 = bfx2(&A[(long long)s1  * 128 + lane * 2]);
        float2 w2 = bfx2(&A[(long long)s2  * 128 + lane * 2]);
        float2 w3 = bfx2(&A[(long long)s3  * 128 + lane * 2]);
        ax += w0.x * c0 + w1.x * c1 + w2.x * c2 + w3.x * c3;
        ay += w0.y * c0 + w1.y * c1 + w2.y * c2 + w3.y * c3;
    }
    *reinterpret_cast<float2*>(&out[(long long)wid * 128 + lane * 2]) = make_float2(ax, ay);
}

// ---------------- fused layer-3 gather + mean-pool + MLP head ----------------

__global__ __launch_bounds__(256) void pool_head_k(
        const ushort* __restrict__ A,      // layer-3 GEMM output [N,128] bf16
        const int* __restrict__ csr, const int* __restrict__ deg,
        const float* __restrict__ dinv, const float* __restrict__ b3,
        const int* __restrict__ batch,
        const float* __restrict__ fw1, const float* __restrict__ fb1,
        const float* __restrict__ fw2, const float* __restrict__ fb2,
        float* __restrict__ out) {
    __shared__ float part[4][HID];
    __shared__ float ps[HID];
    const int g = blockIdx.x;
    const int w = threadIdx.x >> 6, lane = threadIdx.x & 63;

    int start, end;
    {
        int l = 0, h = N_NODES;
        while (l < h) { int m = (l + h) >> 1; if (batch[m] < g) l = m + 1; else h = m; }
        start = l;
        h = N_NODES;
        while (l < h) { int m = (l + h) >> 1; if (batch[m] < g + 1) l = m + 1; else h = m; }
        end = l;
    }

    float sx = 0.f, sy = 0.f;
    const float bx = b3[lane * 2], by = b3[lane * 2 + 1];
    for (int i = start + w; i < end; i += 4) {
        float di = dinv[i];
        float2 v0 = bfx2(&A[(long long)i * 128 + lane * 2]);
        float sc = di * di;
        float ax = v0.x * sc, ay = v0.y * sc;
        int d = deg[i]; if (d > PAD) d = PAD;
        const int4* e4 = reinterpret_cast<const int4*>(csr + i * PAD);
        for (int j0 = 0; j0 < d; j0 += 4) {
            int4 e = e4[j0 >> 2];
            int rem = d - j0;
            int s1 = (rem > 1) ? e.y : e.x;
            int s2 = (rem > 2) ? e.z : e.x;
            int s3 = (rem > 3) ? e.w : e.x;
            float c0 = di * dinv[e.x];
            float c1 = (rem > 1) ? di * dinv[s1] : 0.f;
            float c2 = (rem > 2) ? di * dinv[s2] : 0.f;
            float c3 = (rem > 3) ? di * dinv[s3] : 0.f;
            float2 w0 = bfx2(&A[(long long)e.x * 128 + lane * 2]);
            float2 w1 = bfx2(&A[(long long)s1  * 128 + lane * 2]);
            float2 w2 = bfx2(&A[(long long)s2  * 128 + lane * 2]);
            float2 w3 = bfx2(&A[(long long)s3  * 128 + lane * 2]);
            ax += w0.x * c0 + w1.x * c1 + w2.x * c2 + w3.x * c3;
            ay += w0.y * c0 + w1.y * c1 + w2.y * c2 + w3.y * c3;
        }
        sx += fmaxf(ax + bx, 0.f);
        sy += fmaxf(ay + by, 0.f);
    }
    part[w][lane * 2] = sx;
    part[w][lane * 2 + 1] = sy;
    __syncthreads();

    if (w == 0) {
        float inv = (end > start) ? 1.0f / (float)(end - start) : 0.0f;
        ps[lane * 2]     = (part[0][lane * 2]     + part[1][lane * 2]     + part[2][lane * 2]     + part[3][lane * 2])     * inv;
        ps[lane * 2 + 1] = (part[0][lane * 2 + 1] + part[1][lane * 2 + 1] + part[2][lane * 2 + 1] + part[3][lane * 2 + 1]) * inv;
    }
    __syncthreads();

    if (w == 0) {
        float acc = fb1[lane];
        #pragma unroll 8
        for (int k = 0; k < HID; ++k) acc = fmaf(ps[k], fw1[k * 64 + lane], acc);
        float v = fmaxf(acc, 0.0f) * fw2[lane];
        #pragma unroll
        for (int off = 32; off > 0; off >>= 1) v += __shfl_down(v, off);
        if (lane == 0) out[g] = v + fb2[0];
    }
}

// ---------------- launch ----------------

extern "C" void kernel_launch(void* const* d_in, const int* in_sizes, int n_in,
                              void* d_out, int out_size, void* d_ws, size_t ws_size,
                              hipStream_t stream) {
    const float* x     = (const float*)d_in[0];
    const int*   ei    = (const int*)d_in[1];
    const int*   batch = (const int*)d_in[2];
    const float* W1 = (const float*)d_in[3];
    const float* b1 = (const float*)d_in[4];
    const float* W2 = (const float*)d_in[5];
    const float* b2 = (const float*)d_in[6];
    const float* W3 = (const float*)d_in[7];
    const float* b3 = (const float*)d_in[8];
    const float* fw1 = (const float*)d_in[9];
    const float* fb1 = (const float*)d_in[10];
    const float* fw2 = (const float*)d_in[11];
    const float* fb2 = (const float*)d_in[12];
    float* out = (float*)d_out;

    const int* src = ei;
    const int* dst = ei + N_EDGES;

    // workspace layout (~165 MB)
    char* p = (char*)d_ws;
    float* dinv = (float*)p;  p += 100352 * 4;
    int*   cur  = (int*)p;    p += 100352 * 4;
    int*   csr  = (int*)p;    p += (size_t)N_NODES * PAD * 4;
    ushort* w2h = (ushort*)p; p += 256 * 256 * 2;
    ushort* w2l = (ushort*)p; p += 256 * 256 * 2;
    ushort* w3h = (ushort*)p; p += 256 * 256 * 2;
    ushort* w3l = (ushort*)p; p += 256 * 256 * 2;
    ushort* xb  = (ushort*)p; p += (size_t)N_NODES * 80 * 2;
    float* xpad = (float*)p;  p += (size_t)N_NODES * 80 * 4;
    ushort* buf1 = (ushort*)p; p += (size_t)N_NODES * 128 * 2;
    float*  buf2 = (float*)p;  p += (size_t)N_NODES * 128 * 4;
    ushort* buf3 = (ushort*)p; p += (size_t)N_NODES * 128 * 2;

    const int T = 256;
    const int gw = (N_NODES * 64 + T - 1) / T;  // one wave per node

    // CSR + dinv + x->bf16
    zero_int_k<<<(N_NODES + T - 1) / T, T, 0, stream>>>(cur, N_NODES);
    fill_csr_k<<<(N_EDGES + T - 1) / T, T, 0, stream>>>(src, dst, cur, csr);
    dinv_k<<<(N_NODES + T - 1) / T, T, 0, stream>>>(cur, dinv, N_NODES);
    x2bf_k<<<(N_NODES * 80 + T - 1) / T, T, 0, stream>>>(x, xb);

    // layer 1: gather-first on 78 feats (bf16 rows), GEMM (K=80 padded) + bias + relu -> bf16
    gather78_k<<<gw, T, 0, stream>>>(xb, csr, cur, dinv, xpad);
    prep_wt_k<<<(128 * 256 + T - 1) / T, T, 0, stream>>>(W1, w2h, w2l, NODE_F, 128);
    gemm_mfma_k<<<dim3(782, 1), 256, 0, stream>>>(xpad, 80, 80, N_NODES, w2h, w2l, b1, buf1, 128);

    // layer 2 gather (bf16 rows -> fp32), then fused L2+L3 GEMM -> bf16
    gather128_k<<<gw, T, 0, stream>>>(buf1, csr, cur, dinv, buf2);
    prep_wt_k<<<(256 * 256 + T - 1) / T, T, 0, stream>>>(W2, w2h, w2l, HID, 256);
    prep_wt_k<<<(128 * 256 + T - 1) / T, T, 0, stream>>>(W3, w3h, w3l, 2 * HID, 128);
    gemm23_k<<<1563, 256, 0, stream>>>(buf2, w2h, w2l, b2, w3h, w3l, buf3, N_NODES);

    // layer-3 gather + bias + relu + mean-pool + MLP head (bf16 rows)
    pool_head_k<<<N_GRAPHS, 256, 0, stream>>>(buf3, csr, cur, dinv, b3, batch,
                                              fw1, fb1, fw2, fb2, out);
}

// Round 8
// 341.585 us; speedup vs baseline: 4.1009x; 1.0830x over previous
//
#include <hip/hip_runtime.h>

#define N_NODES 100000
#define N_EDGES 400000
#define N_GRAPHS 2000
#define NODE_F 78
#define HID 128
#define PAD 32
#define SENT N_NODES   // sentinel row index (zeroed row appended to gathered buffers)

typedef __attribute__((ext_vector_type(8))) short short8v;
typedef __attribute__((ext_vector_type(4))) float f32x4;

__device__ __forceinline__ ushort f2bf(float f) {
    unsigned u = __float_as_uint(f);
    unsigned r = (u + 0x7FFFu + ((u >> 16) & 1u)) >> 16;  // round-to-nearest-even
    return (ushort)r;
}
__device__ __forceinline__ float bf2f(ushort b) {
    return __uint_as_float(((unsigned)b) << 16);
}
// load 2 consecutive bf16 as floats (one 4B load)
__device__ __forceinline__ float2 bfx2(const ushort* p) {
    unsigned u = *reinterpret_cast<const unsigned*>(p);
    return make_float2(__uint_as_float(u << 16), __uint_as_float(u & 0xffff0000u));
}

// ---------------- setup: zero cursor, sentinel-fill csr, zero sentinel rows ----------------

__global__ void setup_k(int* __restrict__ cursor, int4* __restrict__ csr4,
                        ushort* __restrict__ xb, ushort* __restrict__ b1,
                        ushort* __restrict__ b3) {
    int i = blockIdx.x * blockDim.x + threadIdx.x;
    if (i < N_NODES * PAD / 4) csr4[i] = make_int4(SENT, SENT, SENT, SENT);
    if (i < N_NODES) cursor[i] = 0;
    if (i < 80) xb[(size_t)N_NODES * 80 + i] = 0;
    if (i < 128) {
        b1[(size_t)N_NODES * 128 + i] = 0;
        b3[(size_t)N_NODES * 128 + i] = 0;
    }
}

__global__ void fill_csr_k(const int* __restrict__ src, const int* __restrict__ dst,
                           int* __restrict__ cursor, int* __restrict__ csr) {
    int e = blockIdx.x * blockDim.x + threadIdx.x;
    if (e >= N_EDGES) return;
    int s = src[e], d = dst[e];
    int p = atomicAdd(&cursor[d], 1);
    if (p < PAD) csr[d * PAD + p] = s;
}

__global__ void dinv_k(const int* __restrict__ deg, float* __restrict__ dinv, int n) {
    int i = blockIdx.x * blockDim.x + threadIdx.x;
    if (i < n) dinv[i] = rsqrtf((float)deg[i] + 1.0f);
}

// ---------------- x -> bf16 pre-scaled by dinv[row], padded to 80 cols ----------------

__global__ void x2bf_k(const float* __restrict__ x, const float* __restrict__ dinv,
                       ushort* __restrict__ xb) {
    int idx = blockIdx.x * blockDim.x + threadIdx.x;
    if (idx >= N_NODES * 80) return;
    int n = idx / 80, f = idx - n * 80;
    xb[idx] = (f < NODE_F) ? f2bf(x[(long long)n * NODE_F + f] * dinv[n]) : (ushort)0;
}

// ---------------- weight prep: W[K][N] fp32 -> bf16 [N][256], zero-padded ----------------

__global__ void prep_wt_k(const float* __restrict__ W, ushort* __restrict__ Wth,
                          int K, int N) {
    int idx = blockIdx.x * blockDim.x + threadIdx.x;
    if (idx >= N * 256) return;
    int n = idx >> 8, k = idx & 255;
    Wth[idx] = (k < K) ? f2bf(W[(long long)k * N + n]) : (ushort)0;
}

// ---------------- split-bf16 MFMA GEMM (layer 1): C_bf16 = relu(A@W + b) * dinv[row] ----------------
// 2-term: (Ah+Al)·Wh. BM=128, BN=128, BK=64, 4 waves.

__global__ __launch_bounds__(256) void gemm_mfma_k(
        const float* __restrict__ A, int lda, int K, int M,
        const ushort* __restrict__ Wth, const float* __restrict__ bias,
        const float* __restrict__ dinv, ushort* __restrict__ C, int N) {
    __shared__ ushort Ah[128 * 64];
    __shared__ ushort Al[128 * 64];
    __shared__ ushort Bh[128 * 64];
    const int tid = threadIdx.x;
    const int w = tid >> 6, l = tid & 63;
    const int bm = blockIdx.x * 128;
    const int bn = blockIdx.y * 128;

    f32x4 acc[2][8];
    #pragma unroll
    for (int m = 0; m < 2; ++m)
        #pragma unroll
        for (int j = 0; j < 8; ++j)
            acc[m][j] = (f32x4){0.f, 0.f, 0.f, 0.f};

    for (int k0 = 0; k0 < K; k0 += 64) {
        __syncthreads();
        #pragma unroll
        for (int i = 0; i < 8; ++i) {
            int idx = tid + i * 256;
            int r = idx >> 4;
            int kq = (idx & 15) * 4;
            ushort4 h4, l4;
            if (k0 + kq < K) {
                int gr = bm + r; if (gr >= M) gr = M - 1;
                float4 v = *reinterpret_cast<const float4*>(&A[(long long)gr * lda + k0 + kq]);
                h4.x = f2bf(v.x); l4.x = f2bf(v.x - bf2f(h4.x));
                h4.y = f2bf(v.y); l4.y = f2bf(v.y - bf2f(h4.y));
                h4.z = f2bf(v.z); l4.z = f2bf(v.z - bf2f(h4.z));
                h4.w = f2bf(v.w); l4.w = f2bf(v.w - bf2f(h4.w));
            } else {
                h4 = (ushort4){0, 0, 0, 0};
                l4 = (ushort4){0, 0, 0, 0};
            }
            int e = r * 64 + ((kq >> 3) ^ (r & 7)) * 8 + (kq & 7);
            *reinterpret_cast<ushort4*>(&Ah[e]) = h4;
            *reinterpret_cast<ushort4*>(&Al[e]) = l4;
        }
        #pragma unroll
        for (int i = 0; i < 4; ++i) {
            int idx = tid + i * 256;
            int n = idx >> 3, s0 = idx & 7;
            long long g = (long long)(bn + n) * 256 + k0 + s0 * 8;
            short8v vh = *reinterpret_cast<const short8v*>(&Wth[g]);
            int e = n * 64 + (s0 ^ (n & 7)) * 8;
            *reinterpret_cast<short8v*>(&Bh[e]) = vh;
        }
        __syncthreads();
        #pragma unroll
        for (int ks = 0; ks < 2; ++ks) {
            short8v ah[2], al[2];
            #pragma unroll
            for (int m = 0; m < 2; ++m) {
                int r = w * 32 + m * 16 + (l & 15);
                int e = r * 64 + ((ks * 4 + (l >> 4)) ^ (r & 7)) * 8;
                ah[m] = *reinterpret_cast<const short8v*>(&Ah[e]);
                al[m] = *reinterpret_cast<const short8v*>(&Al[e]);
            }
            #pragma unroll
            for (int j = 0; j < 8; ++j) {
                int n = j * 16 + (l & 15);
                int e = n * 64 + ((ks * 4 + (l >> 4)) ^ (n & 7)) * 8;
                short8v bh = *reinterpret_cast<const short8v*>(&Bh[e]);
                #pragma unroll
                for (int m = 0; m < 2; ++m) {
                    acc[m][j] = __builtin_amdgcn_mfma_f32_16x16x32_bf16(ah[m], bh, acc[m][j], 0, 0, 0);
                    acc[m][j] = __builtin_amdgcn_mfma_f32_16x16x32_bf16(al[m], bh, acc[m][j], 0, 0, 0);
                }
            }
        }
    }

    // epilogue: relu(acc + bias) * dinv[row] -> bf16
    float dv[2][4];
    #pragma unroll
    for (int m = 0; m < 2; ++m)
        #pragma unroll
        for (int rg = 0; rg < 4; ++rg) {
            int gr = bm + w * 32 + m * 16 + (l >> 4) * 4 + rg;
            dv[m][rg] = (gr < M) ? dinv[gr] : 0.f;
        }
    #pragma unroll
    for (int j = 0; j < 8; ++j) {
        int gc = bn + j * 16 + (l & 15);
        float bv = bias[gc];
        #pragma unroll
        for (int m = 0; m < 2; ++m) {
            #pragma unroll
            for (int rg = 0; rg < 4; ++rg) {
                int gr = bm + w * 32 + m * 16 + (l >> 4) * 4 + rg;
                if (gr < M)
                    C[(long long)gr * N + gc] = f2bf(fmaxf(acc[m][j][rg] + bv, 0.0f) * dv[m][rg]);
            }
        }
    }
}

// ---------------- fused layer2+layer3 GEMM: C3_bf16 = (relu(A@W2+b2) @ W3) * dinv[row] ----------------
// 2-term splits: (Ah+Al)·W2h, (Th+Tl)·W3h. BM=64, 4 waves, wave owns 16 rows.

__global__ __launch_bounds__(256) void gemm23_k(
        const float* __restrict__ A,   // [M,128] fp32 (aggregated layer-1 output)
        const ushort* __restrict__ W2h, const float* __restrict__ b2,
        const ushort* __restrict__ W3h, const float* __restrict__ dinv,
        ushort* __restrict__ C, int M) {
    __shared__ ushort Ah[64 * 64];
    __shared__ ushort Al[64 * 64];
    __shared__ ushort Bh[128 * 64];
    const int tid = threadIdx.x;
    const int w = tid >> 6, l = tid & 63;
    const int bm = blockIdx.x * 64;

    f32x4 acc2[16];
    #pragma unroll
    for (int j = 0; j < 16; ++j) acc2[j] = (f32x4){0.f, 0.f, 0.f, 0.f};

    // ---- phase 1: T = A @ W2 (K=128) ----
    for (int k0 = 0; k0 < 128; k0 += 64) {
        __syncthreads();
        #pragma unroll
        for (int i = 0; i < 4; ++i) {
            int idx = tid + i * 256;
            int r = idx >> 4;
            int kq = (idx & 15) * 4;
            int gr = bm + r; if (gr >= M) gr = M - 1;
            float4 v = *reinterpret_cast<const float4*>(&A[(long long)gr * 128 + k0 + kq]);
            ushort4 h4, l4;
            h4.x = f2bf(v.x); l4.x = f2bf(v.x - bf2f(h4.x));
            h4.y = f2bf(v.y); l4.y = f2bf(v.y - bf2f(h4.y));
            h4.z = f2bf(v.z); l4.z = f2bf(v.z - bf2f(h4.z));
            h4.w = f2bf(v.w); l4.w = f2bf(v.w - bf2f(h4.w));
            int e = r * 64 + ((kq >> 3) ^ (r & 7)) * 8 + (kq & 7);
            *reinterpret_cast<ushort4*>(&Ah[e]) = h4;
            *reinterpret_cast<ushort4*>(&Al[e]) = l4;
        }
        #pragma unroll
        for (int nh = 0; nh < 2; ++nh) {
            if (nh) __syncthreads();
            #pragma unroll
            for (int i = 0; i < 4; ++i) {
                int idx = tid + i * 256;
                int n = idx >> 3, s0 = idx & 7;
                long long g = (long long)(nh * 128 + n) * 256 + k0 + s0 * 8;
                short8v vh = *reinterpret_cast<const short8v*>(&W2h[g]);
                int e = n * 64 + (s0 ^ (n & 7)) * 8;
                *reinterpret_cast<short8v*>(&Bh[e]) = vh;
            }
            __syncthreads();
            #pragma unroll
            for (int ks = 0; ks < 2; ++ks) {
                int r = w * 16 + (l & 15);
                int ea = r * 64 + ((ks * 4 + (l >> 4)) ^ (r & 7)) * 8;
                short8v ah = *reinterpret_cast<const short8v*>(&Ah[ea]);
                short8v al = *reinterpret_cast<const short8v*>(&Al[ea]);
                #pragma unroll
                for (int jl = 0; jl < 8; ++jl) {
                    int n = jl * 16 + (l & 15);
                    int e = n * 64 + ((ks * 4 + (l >> 4)) ^ (n & 7)) * 8;
                    short8v bh = *reinterpret_cast<const short8v*>(&Bh[e]);
                    int j = nh * 8 + jl;
                    acc2[j] = __builtin_amdgcn_mfma_f32_16x16x32_bf16(ah, bh, acc2[j], 0, 0, 0);
                    acc2[j] = __builtin_amdgcn_mfma_f32_16x16x32_bf16(al, bh, acc2[j], 0, 0, 0);
                }
            }
        }
    }

    // ---- phase 2: C3 = relu(T + b2) @ W3, K=256 in 4 chunks of 64 ----
    f32x4 acc3[8];
    #pragma unroll
    for (int j = 0; j < 8; ++j) acc3[j] = (f32x4){0.f, 0.f, 0.f, 0.f};

    #pragma unroll
    for (int ch = 0; ch < 4; ++ch) {
        __syncthreads();
        #pragma unroll
        for (int jj = 0; jj < 4; ++jj) {
            int j = ch * 4 + jj;
            float bv = b2[j * 16 + (l & 15)];
            #pragma unroll
            for (int rg = 0; rg < 4; ++rg) {
                int r = w * 16 + (l >> 4) * 4 + rg;
                float v = fmaxf(acc2[j][rg] + bv, 0.f);
                ushort h = f2bf(v);
                ushort lo = f2bf(v - bf2f(h));
                int cl = jj * 16 + (l & 15);
                int e = r * 64 + ((cl >> 3) ^ (r & 7)) * 8 + (cl & 7);
                Ah[e] = h; Al[e] = lo;
            }
        }
        #pragma unroll
        for (int i = 0; i < 4; ++i) {
            int idx = tid + i * 256;
            int n = idx >> 3, s0 = idx & 7;
            long long g = (long long)n * 256 + ch * 64 + s0 * 8;
            short8v vh = *reinterpret_cast<const short8v*>(&W3h[g]);
            int e = n * 64 + (s0 ^ (n & 7)) * 8;
            *reinterpret_cast<short8v*>(&Bh[e]) = vh;
        }
        __syncthreads();
        #pragma unroll
        for (int ks = 0; ks < 2; ++ks) {
            int r = w * 16 + (l & 15);
            int ea = r * 64 + ((ks * 4 + (l >> 4)) ^ (r & 7)) * 8;
            short8v ah = *reinterpret_cast<const short8v*>(&Ah[ea]);
            short8v al = *reinterpret_cast<const short8v*>(&Al[ea]);
            #pragma unroll
            for (int j3 = 0; j3 < 8; ++j3) {
                int n = j3 * 16 + (l & 15);
                int e = n * 64 + ((ks * 4 + (l >> 4)) ^ (n & 7)) * 8;
                short8v bh = *reinterpret_cast<const short8v*>(&Bh[e]);
                acc3[j3] = __builtin_amdgcn_mfma_f32_16x16x32_bf16(ah, bh, acc3[j3], 0, 0, 0);
                acc3[j3] = __builtin_amdgcn_mfma_f32_16x16x32_bf16(al, bh, acc3[j3], 0, 0, 0);
            }
        }
    }

    // epilogue: pre-scale by dinv[row] (buf3 is gathered next) -> bf16
    float dv[4];
    #pragma unroll
    for (int rg = 0; rg < 4; ++rg) {
        int gr = bm + w * 16 + (l >> 4) * 4 + rg;
        dv[rg] = (gr < M) ? dinv[gr] : 0.f;
    }
    #pragma unroll
    for (int j = 0; j < 8; ++j) {
        int gc = j * 16 + (l & 15);
        #pragma unroll
        for (int rg = 0; rg < 4; ++rg) {
            int gr = bm + w * 16 + (l >> 4) * 4 + rg;
            if (gr < M) C[(long long)gr * 128 + gc] = f2bf(acc3[j][rg] * dv[rg]);
        }
    }
}

// ---------------- gathers: pure row sums (rows pre-scaled, sentinel-padded CSR) ----------------

// out[i] = dinv[i] * sum of pre-scaled rows {i} u N(i), fp32 [N,80]
__global__ __launch_bounds__(256) void gather78_k(const ushort* __restrict__ Xb,
        const int* __restrict__ deg, const int* __restrict__ csr,
        const float* __restrict__ dinv, float* __restrict__ out) {
    int wid = (blockIdx.x * blockDim.x + threadIdx.x) >> 6;
    int lane = threadIdx.x & 63;
    if (wid >= N_NODES) return;
    float di = dinv[wid];
    float ax = 0.f, ay = 0.f;
    bool act = lane < 40;
    if (act) {
        float2 v = bfx2(&Xb[(size_t)wid * 80 + lane * 2]);
        ax = v.x; ay = v.y;
    }
    int d = deg[wid]; if (d > PAD) d = PAD;
    const int4* e4 = reinterpret_cast<const int4*>(csr + wid * PAD);
    for (int j0 = 0; j0 < d; j0 += 4) {
        int4 e = e4[j0 >> 2];
        if (act) {
            float2 v0 = bfx2(&Xb[(size_t)e.x * 80 + lane * 2]);
            float2 v1 = bfx2(&Xb[(size_t)e.y * 80 + lane * 2]);
            float2 v2 = bfx2(&Xb[(size_t)e.z * 80 + lane * 2]);
            float2 v3 = bfx2(&Xb[(size_t)e.w * 80 + lane * 2]);
            ax += v0.x + v1.x + v2.x + v3.x;
            ay += v0.y + v1.y + v2.y + v3.y;
        }
    }
    if (act)
        *reinterpret_cast<float2*>(&out[(size_t)wid * 80 + lane * 2]) = make_float2(ax * di, ay * di);
}

// out[i] = dinv[i] * sum of pre-scaled rows, fp32 [N,128]
__global__ __launch_bounds__(256) void gather128_k(const ushort* __restrict__ A,
        const int* __restrict__ deg, const int* __restrict__ csr,
        const float* __restrict__ dinv, float* __restrict__ out) {
    int wid = (blockIdx.x * blockDim.x + threadIdx.x) >> 6;
    int lane = threadIdx.x & 63;
    if (wid >= N_NODES) return;
    float di = dinv[wid];
    float2 v = bfx2(&A[(size_t)wid * 128 + lane * 2]);
    float ax = v.x, ay = v.y;
    int d = deg[wid]; if (d > PAD) d = PAD;
    const int4* e4 = reinterpret_cast<const int4*>(csr + wid * PAD);
    for (int j0 = 0; j0 < d; j0 += 4) {
        int4 e = e4[j0 >> 2];
        float2 w0 = bfx2(&A[(size_t)e.x * 128 + lane * 2]);
        float2 w1 = bfx2(&A[(size_t)e.y * 128 + lane * 2]);
        float2 w2 = bfx2(&A[(size_t)e.z * 128 + lane * 2]);
        float2 w3 = bfx2(&A[(size_t)e.w * 128 + lane * 2]);
        ax += w0.x + w1.x + w2.x + w3.x;
        ay += w0.y + w1.y + w2.y + w3.y;
    }
    *reinterpret_cast<float2*>(&out[(size_t)wid * 128 + lane * 2]) = make_float2(ax * di, ay * di);
}

// ---------------- fused layer-3 gather + mean-pool + MLP head (8 waves/graph) ----------------

__global__ __launch_bounds__(512) void pool_head_k(
        const ushort* __restrict__ A,      // layer-3 GEMM output [N,128] bf16, pre-scaled
        const int* __restrict__ deg, const int* __restrict__ csr,
        const float* __restrict__ dinv, const float* __restrict__ b3,
        const int* __restrict__ batch,
        const float* __restrict__ fw1, const float* __restrict__ fb1,
        const float* __restrict__ fw2, const float* __restrict__ fb2,
        float* __restrict__ out) {
    __shared__ float part[8][HID];
    __shared__ float ps[HID];
    const int g = blockIdx.x;
    const int w = threadIdx.x >> 6, lane = threadIdx.x & 63;

    int start, end;
    {
        int l = 0, h = N_NODES;
        while (l < h) { int m = (l + h) >> 1; if (batch[m] < g) l = m + 1; else h = m; }
        start = l;
        h = N_NODES;
        while (l < h) { int m = (l + h) >> 1; if (batch[m] < g + 1) l = m + 1; else h = m; }
        end = l;
    }

    float sx = 0.f, sy = 0.f;
    const float bx = b3[lane * 2], by = b3[lane * 2 + 1];
    for (int i = start + w; i < end; i += 8) {
        float di = dinv[i];
        float2 v = bfx2(&A[(size_t)i * 128 + lane * 2]);
        float ax = v.x, ay = v.y;
        int d = deg[i]; if (d > PAD) d = PAD;
        const int4* e4 = reinterpret_cast<const int4*>(csr + i * PAD);
        for (int j0 = 0; j0 < d; j0 += 4) {
            int4 e = e4[j0 >> 2];
            float2 w0 = bfx2(&A[(size_t)e.x * 128 + lane * 2]);
            float2 w1 = bfx2(&A[(size_t)e.y * 128 + lane * 2]);
            float2 w2 = bfx2(&A[(size_t)e.z * 128 + lane * 2]);
            float2 w3 = bfx2(&A[(size_t)e.w * 128 + lane * 2]);
            ax += w0.x + w1.x + w2.x + w3.x;
            ay += w0.y + w1.y + w2.y + w3.y;
        }
        sx += fmaxf(ax * di + bx, 0.f);
        sy += fmaxf(ay * di + by, 0.f);
    }
    part[w][lane * 2] = sx;
    part[w][lane * 2 + 1] = sy;
    __syncthreads();

    if (w == 0) {
        float inv = (end > start) ? 1.0f / (float)(end - start) : 0.0f;
        float s0 = 0.f, s1 = 0.f;
        #pragma unroll
        for (int q = 0; q < 8; ++q) {
            s0 += part[q][lane * 2];
            s1 += part[q][lane * 2 + 1];
        }
        ps[lane * 2] = s0 * inv;
        ps[lane * 2 + 1] = s1 * inv;
    }
    __syncthreads();

    if (w == 0) {
        float acc = fb1[lane];
        #pragma unroll 8
        for (int k = 0; k < HID; ++k) acc = fmaf(ps[k], fw1[k * 64 + lane], acc);
        float v = fmaxf(acc, 0.0f) * fw2[lane];
        #pragma unroll
        for (int off = 32; off > 0; off >>= 1) v += __shfl_down(v, off);
        if (lane == 0) out[g] = v + fb2[0];
    }
}

// ---------------- launch ----------------

extern "C" void kernel_launch(void* const* d_in, const int* in_sizes, int n_in,
                              void* d_out, int out_size, void* d_ws, size_t ws_size,
                              hipStream_t stream) {
    const float* x     = (const float*)d_in[0];
    const int*   ei    = (const int*)d_in[1];
    const int*   batch = (const int*)d_in[2];
    const float* W1 = (const float*)d_in[3];
    const float* b1 = (const float*)d_in[4];
    const float* W2 = (const float*)d_in[5];
    const float* b2 = (const float*)d_in[6];
    const float* W3 = (const float*)d_in[7];
    const float* b3 = (const float*)d_in[8];
    const float* fw1 = (const float*)d_in[9];
    const float* fb1 = (const float*)d_in[10];
    const float* fw2 = (const float*)d_in[11];
    const float* fb2 = (const float*)d_in[12];
    float* out = (float*)d_out;

    const int* src = ei;
    const int* dst = ei + N_EDGES;

    // workspace layout (~164 MB)
    char* p = (char*)d_ws;
    float*  dinv = (float*)p;  p += 100352 * 4;
    int*    cur  = (int*)p;    p += 100352 * 4;
    int*    csr  = (int*)p;    p += (size_t)N_NODES * PAD * 4;
    ushort* w1h  = (ushort*)p; p += 256 * 256 * 2;
    ushort* w2h  = (ushort*)p; p += 256 * 256 * 2;
    ushort* w3h  = (ushort*)p; p += 256 * 256 * 2;
    ushort* xb   = (ushort*)p; p += (size_t)(N_NODES + 1) * 80 * 2;
    float*  xpad = (float*)p;  p += (size_t)N_NODES * 80 * 4;
    ushort* buf1 = (ushort*)p; p += (size_t)(N_NODES + 1) * 128 * 2;
    float*  buf2 = (float*)p;  p += (size_t)N_NODES * 128 * 4;
    ushort* buf3 = (ushort*)p; p += (size_t)(N_NODES + 1) * 128 * 2;

    const int T = 256;
    const int gw = (N_NODES * 64 + T - 1) / T;  // one wave per node

    // setup (cursor=0, csr=SENT, sentinel rows=0), CSR fill, dinv, x->bf16 pre-scaled
    setup_k<<<(N_NODES * PAD / 4 + T - 1) / T, T, 0, stream>>>(cur, (int4*)csr, xb, buf1, buf3);
    fill_csr_k<<<(N_EDGES + T - 1) / T, T, 0, stream>>>(src, dst, cur, csr);
    dinv_k<<<(N_NODES + T - 1) / T, T, 0, stream>>>(cur, dinv, N_NODES);
    x2bf_k<<<(N_NODES * 80 + T - 1) / T, T, 0, stream>>>(x, dinv, xb);

    // weight preps (single bf16 plane)
    prep_wt_k<<<(128 * 256 + T - 1) / T, T, 0, stream>>>(W1, w1h, NODE_F, 128);
    prep_wt_k<<<(256 * 256 + T - 1) / T, T, 0, stream>>>(W2, w2h, HID, 256);
    prep_wt_k<<<(128 * 256 + T - 1) / T, T, 0, stream>>>(W3, w3h, 2 * HID, 128);

    // layer 1: gather-first (pure sum), GEMM K=80 + bias + relu, pre-scaled bf16 out
    gather78_k<<<gw, T, 0, stream>>>(xb, cur, csr, dinv, xpad);
    gemm_mfma_k<<<dim3(782, 1), 256, 0, stream>>>(xpad, 80, 80, N_NODES, w1h, b1, dinv, buf1, 128);

    // layer 2 gather, then fused L2+L3 GEMM, pre-scaled bf16 out
    gather128_k<<<gw, T, 0, stream>>>(buf1, cur, csr, dinv, buf2);
    gemm23_k<<<1563, 256, 0, stream>>>(buf2, w2h, b2, w3h, dinv, buf3, N_NODES);

    // layer-3 gather + bias + relu + mean-pool + MLP head
    pool_head_k<<<N_GRAPHS, 512, 0, stream>>>(buf3, cur, csr, dinv, b3, batch,
                                              fw1, fb1, fw2, fb2, out);
}

// Round 9
// 327.024 us; speedup vs baseline: 4.2835x; 1.0445x over previous
//
#include <hip/hip_runtime.h>

#define N_NODES 100000
#define N_EDGES 400000
#define N_GRAPHS 2000
#define NODE_F 78
#define HID 128
#define PAD 32
#define SENT N_NODES   // sentinel row index (zeroed row appended to gathered buffers)

typedef __attribute__((ext_vector_type(8))) short short8v;
typedef __attribute__((ext_vector_type(4))) float f32x4;

__device__ __forceinline__ ushort f2bf(float f) {
    unsigned u = __float_as_uint(f);
    unsigned r = (u + 0x7FFFu + ((u >> 16) & 1u)) >> 16;  // round-to-nearest-even
    return (ushort)r;
}
__device__ __forceinline__ float bf2f(ushort b) {
    return __uint_as_float(((unsigned)b) << 16);
}
// load 2 consecutive bf16 as floats (one 4B load)
__device__ __forceinline__ float2 bfx2(const ushort* p) {
    unsigned u = *reinterpret_cast<const unsigned*>(p);
    return make_float2(__uint_as_float(u << 16), __uint_as_float(u & 0xffff0000u));
}
__device__ __forceinline__ unsigned packbf(float a, float b) {
    return (unsigned)f2bf(a) | ((unsigned)f2bf(b) << 16);
}

// ---------------- setup: zero cursor, sentinel-fill csr, zero sentinel rows ----------------

__global__ void setup_k(int* __restrict__ cursor, int4* __restrict__ csr4,
                        ushort* __restrict__ xb, ushort* __restrict__ b1,
                        ushort* __restrict__ b3) {
    int i = blockIdx.x * blockDim.x + threadIdx.x;
    if (i < N_NODES * PAD / 4) csr4[i] = make_int4(SENT, SENT, SENT, SENT);
    if (i < N_NODES) cursor[i] = 0;
    if (i < 80) xb[(size_t)N_NODES * 80 + i] = 0;
    if (i < 128) {
        b1[(size_t)N_NODES * 128 + i] = 0;
        b3[(size_t)N_NODES * 128 + i] = 0;
    }
}

__global__ void fill_csr_k(const int* __restrict__ src, const int* __restrict__ dst,
                           int* __restrict__ cursor, int* __restrict__ csr) {
    int e = blockIdx.x * blockDim.x + threadIdx.x;
    if (e >= N_EDGES) return;
    int s = src[e], d = dst[e];
    int p = atomicAdd(&cursor[d], 1);
    if (p < PAD) csr[d * PAD + p] = s;
}

__global__ void dinv_k(const int* __restrict__ deg, float* __restrict__ dinv, int n) {
    int i = blockIdx.x * blockDim.x + threadIdx.x;
    if (i < n) dinv[i] = rsqrtf((float)deg[i] + 1.0f);
}

// ---------------- x -> bf16 pre-scaled by dinv[row], padded to 80 cols ----------------

__global__ void x2bf_k(const float* __restrict__ x, const float* __restrict__ dinv,
                       ushort* __restrict__ xb) {
    int idx = blockIdx.x * blockDim.x + threadIdx.x;
    if (idx >= N_NODES * 80) return;
    int n = idx / 80, f = idx - n * 80;
    xb[idx] = (f < NODE_F) ? f2bf(x[(long long)n * NODE_F + f] * dinv[n]) : (ushort)0;
}

// ---------------- weight prep: W[K][N] fp32 -> bf16 [N][256], zero-padded ----------------

__global__ void prep_wt_k(const float* __restrict__ W, ushort* __restrict__ Wth,
                          int K, int N) {
    int idx = blockIdx.x * blockDim.x + threadIdx.x;
    if (idx >= N * 256) return;
    int n = idx >> 8, k = idx & 255;
    Wth[idx] = (k < K) ? f2bf(W[(long long)k * N + n]) : (ushort)0;
}

// ---------------- layer-1 GEMM: C_bf16 = relu(A_bf16[M,80] @ W1 + b1) * dinv[row] ----------------
// 1-term bf16 MFMA. BM=128, BN=128, K=80 (2 k-steps of 64, second mostly padded). 4 waves.

__global__ __launch_bounds__(256) void gemm1_k(
        const ushort* __restrict__ A, int M,
        const ushort* __restrict__ Wth, const float* __restrict__ bias,
        const float* __restrict__ dinv, ushort* __restrict__ C) {
    __shared__ ushort At[128 * 64];
    __shared__ ushort Bh[128 * 64];
    const int tid = threadIdx.x;
    const int w = tid >> 6, l = tid & 63;
    const int bm = blockIdx.x * 128;

    f32x4 acc[2][8];
    #pragma unroll
    for (int m = 0; m < 2; ++m)
        #pragma unroll
        for (int j = 0; j < 8; ++j)
            acc[m][j] = (f32x4){0.f, 0.f, 0.f, 0.f};

    for (int k0 = 0; k0 < 128; k0 += 64) {
        __syncthreads();
        // stage A tile 128x64 bf16 (plain copies; K=80 guard)
        #pragma unroll
        for (int i = 0; i < 4; ++i) {
            int idx = tid + i * 256;           // 1024 slots = 128 rows x 8 chunks
            int r = idx >> 3, s0 = idx & 7;
            int gr = bm + r; if (gr >= M) gr = M - 1;
            int kk = k0 + s0 * 8;
            short8v v;
            if (kk < 80) v = *reinterpret_cast<const short8v*>(&A[(size_t)gr * 80 + kk]);
            else v = (short8v){0,0,0,0,0,0,0,0};
            *reinterpret_cast<short8v*>(&At[r * 64 + (s0 ^ (r & 7)) * 8]) = v;
        }
        // stage W1 tile 128n x 64k
        #pragma unroll
        for (int i = 0; i < 4; ++i) {
            int idx = tid + i * 256;
            int n = idx >> 3, s0 = idx & 7;
            long long g = (long long)n * 256 + k0 + s0 * 8;
            *reinterpret_cast<short8v*>(&Bh[n * 64 + (s0 ^ (n & 7)) * 8]) =
                *reinterpret_cast<const short8v*>(&Wth[g]);
        }
        __syncthreads();
        #pragma unroll
        for (int ks = 0; ks < 2; ++ks) {
            short8v ah[2];
            #pragma unroll
            for (int m = 0; m < 2; ++m) {
                int r = w * 32 + m * 16 + (l & 15);
                ah[m] = *reinterpret_cast<const short8v*>(
                    &At[r * 64 + ((ks * 4 + (l >> 4)) ^ (r & 7)) * 8]);
            }
            #pragma unroll
            for (int j = 0; j < 8; ++j) {
                int n = j * 16 + (l & 15);
                short8v bh = *reinterpret_cast<const short8v*>(
                    &Bh[n * 64 + ((ks * 4 + (l >> 4)) ^ (n & 7)) * 8]);
                #pragma unroll
                for (int m = 0; m < 2; ++m)
                    acc[m][j] = __builtin_amdgcn_mfma_f32_16x16x32_bf16(ah[m], bh, acc[m][j], 0, 0, 0);
            }
        }
    }

    // epilogue: relu(acc + bias) * dinv[row] -> bf16
    float dv[2][4];
    #pragma unroll
    for (int m = 0; m < 2; ++m)
        #pragma unroll
        for (int rg = 0; rg < 4; ++rg) {
            int gr = bm + w * 32 + m * 16 + (l >> 4) * 4 + rg;
            dv[m][rg] = (gr < M) ? dinv[gr] : 0.f;
        }
    #pragma unroll
    for (int j = 0; j < 8; ++j) {
        int gc = j * 16 + (l & 15);
        float bv = bias[gc];
        #pragma unroll
        for (int m = 0; m < 2; ++m) {
            #pragma unroll
            for (int rg = 0; rg < 4; ++rg) {
                int gr = bm + w * 32 + m * 16 + (l >> 4) * 4 + rg;
                if (gr < M)
                    C[(size_t)gr * 128 + gc] = f2bf(fmaxf(acc[m][j][rg] + bv, 0.0f) * dv[m][rg]);
            }
        }
    }
}

// ---------------- fused layer2+layer3 GEMM: C3_bf16 = (relu(A_bf16@W2+b2) @ W3) * dinv[row] ----------------
// 1-term MFMAs. BM=128, 512 threads = 8 waves; wave w owns rows w*16..w*16+15.

__global__ __launch_bounds__(512) void gemm23_k(
        const ushort* __restrict__ A,   // [M,128] bf16 (aggregated layer-1 output)
        const ushort* __restrict__ W2h, const float* __restrict__ b2,
        const ushort* __restrict__ W3h, const float* __restrict__ dinv,
        ushort* __restrict__ C, int M) {
    __shared__ ushort At[128 * 64];
    __shared__ ushort Bh[128 * 64];
    const int tid = threadIdx.x;
    const int w = tid >> 6, l = tid & 63;
    const int bm = blockIdx.x * 128;

    f32x4 acc2[16];
    #pragma unroll
    for (int j = 0; j < 16; ++j) acc2[j] = (f32x4){0.f, 0.f, 0.f, 0.f};

    // ---- phase 1: T = A @ W2 (K=128) ----
    for (int k0 = 0; k0 < 128; k0 += 64) {
        __syncthreads();
        // stage A tile 128x64 bf16 (plain copies)
        #pragma unroll
        for (int i = 0; i < 2; ++i) {
            int idx = tid + i * 512;           // 1024 slots
            int r = idx >> 3, s0 = idx & 7;
            int gr = bm + r; if (gr >= M) gr = M - 1;
            *reinterpret_cast<short8v*>(&At[r * 64 + (s0 ^ (r & 7)) * 8]) =
                *reinterpret_cast<const short8v*>(&A[(size_t)gr * 128 + k0 + s0 * 8]);
        }
        #pragma unroll
        for (int nh = 0; nh < 2; ++nh) {
            if (nh) __syncthreads();
            // stage W2 half tile [128n x 64k]
            #pragma unroll
            for (int i = 0; i < 2; ++i) {
                int idx = tid + i * 512;
                int n = idx >> 3, s0 = idx & 7;
                long long g = (long long)(nh * 128 + n) * 256 + k0 + s0 * 8;
                *reinterpret_cast<short8v*>(&Bh[n * 64 + (s0 ^ (n & 7)) * 8]) =
                    *reinterpret_cast<const short8v*>(&W2h[g]);
            }
            __syncthreads();
            #pragma unroll
            for (int ks = 0; ks < 2; ++ks) {
                int r = w * 16 + (l & 15);
                short8v ah = *reinterpret_cast<const short8v*>(
                    &At[r * 64 + ((ks * 4 + (l >> 4)) ^ (r & 7)) * 8]);
                #pragma unroll
                for (int jl = 0; jl < 8; ++jl) {
                    int n = jl * 16 + (l & 15);
                    short8v bh = *reinterpret_cast<const short8v*>(
                        &Bh[n * 64 + ((ks * 4 + (l >> 4)) ^ (n & 7)) * 8]);
                    acc2[nh * 8 + jl] = __builtin_amdgcn_mfma_f32_16x16x32_bf16(ah, bh, acc2[nh * 8 + jl], 0, 0, 0);
                }
            }
        }
    }

    // ---- phase 2: C3 = relu(T + b2) @ W3, K=256 in 4 chunks of 64; T single bf16 plane ----
    f32x4 acc3[8];
    #pragma unroll
    for (int j = 0; j < 8; ++j) acc3[j] = (f32x4){0.f, 0.f, 0.f, 0.f};

    #pragma unroll
    for (int ch = 0; ch < 4; ++ch) {
        __syncthreads();   // previous chunk (or phase-1) LDS reads complete
        // write T chunk (cols ch*64..+64) as bf16 into At
        #pragma unroll
        for (int jj = 0; jj < 4; ++jj) {
            int j = ch * 4 + jj;
            float bv = b2[j * 16 + (l & 15)];
            #pragma unroll
            for (int rg = 0; rg < 4; ++rg) {
                int r = w * 16 + (l >> 4) * 4 + rg;
                int cl = jj * 16 + (l & 15);
                At[r * 64 + ((cl >> 3) ^ (r & 7)) * 8 + (cl & 7)] =
                    f2bf(fmaxf(acc2[j][rg] + bv, 0.f));
            }
        }
        // stage W3 chunk tile [128n x 64k]
        #pragma unroll
        for (int i = 0; i < 2; ++i) {
            int idx = tid + i * 512;
            int n = idx >> 3, s0 = idx & 7;
            long long g = (long long)n * 256 + ch * 64 + s0 * 8;
            *reinterpret_cast<short8v*>(&Bh[n * 64 + (s0 ^ (n & 7)) * 8]) =
                *reinterpret_cast<const short8v*>(&W3h[g]);
        }
        __syncthreads();
        #pragma unroll
        for (int ks = 0; ks < 2; ++ks) {
            int r = w * 16 + (l & 15);
            short8v ah = *reinterpret_cast<const short8v*>(
                &At[r * 64 + ((ks * 4 + (l >> 4)) ^ (r & 7)) * 8]);
            #pragma unroll
            for (int j3 = 0; j3 < 8; ++j3) {
                int n = j3 * 16 + (l & 15);
                short8v bh = *reinterpret_cast<const short8v*>(
                    &Bh[n * 64 + ((ks * 4 + (l >> 4)) ^ (n & 7)) * 8]);
                acc3[j3] = __builtin_amdgcn_mfma_f32_16x16x32_bf16(ah, bh, acc3[j3], 0, 0, 0);
            }
        }
    }

    // epilogue: pre-scale by dinv[row] (buf3 is gathered next) -> bf16
    float dv[4];
    #pragma unroll
    for (int rg = 0; rg < 4; ++rg) {
        int gr = bm + w * 16 + (l >> 4) * 4 + rg;
        dv[rg] = (gr < M) ? dinv[gr] : 0.f;
    }
    #pragma unroll
    for (int j = 0; j < 8; ++j) {
        int gc = j * 16 + (l & 15);
        #pragma unroll
        for (int rg = 0; rg < 4; ++rg) {
            int gr = bm + w * 16 + (l >> 4) * 4 + rg;
            if (gr < M) C[(size_t)gr * 128 + gc] = f2bf(acc3[j][rg] * dv[rg]);
        }
    }
}

// ---------------- gathers: pure row sums, bf16 in AND out ----------------

// out[i] = bf16( dinv[i] * sum of pre-scaled rows {i} u N(i) ), [N,80]
__global__ __launch_bounds__(256) void gather78_k(const ushort* __restrict__ Xb,
        const int* __restrict__ deg, const int* __restrict__ csr,
        const float* __restrict__ dinv, ushort* __restrict__ out) {
    int wid = (blockIdx.x * blockDim.x + threadIdx.x) >> 6;
    int lane = threadIdx.x & 63;
    if (wid >= N_NODES) return;
    float di = dinv[wid];
    float ax = 0.f, ay = 0.f;
    bool act = lane < 40;
    if (act) {
        float2 v = bfx2(&Xb[(size_t)wid * 80 + lane * 2]);
        ax = v.x; ay = v.y;
    }
    int d = deg[wid]; if (d > PAD) d = PAD;
    const int4* e4 = reinterpret_cast<const int4*>(csr + wid * PAD);
    for (int j0 = 0; j0 < d; j0 += 4) {
        int4 e = e4[j0 >> 2];
        if (act) {
            float2 v0 = bfx2(&Xb[(size_t)e.x * 80 + lane * 2]);
            float2 v1 = bfx2(&Xb[(size_t)e.y * 80 + lane * 2]);
            float2 v2 = bfx2(&Xb[(size_t)e.z * 80 + lane * 2]);
            float2 v3 = bfx2(&Xb[(size_t)e.w * 80 + lane * 2]);
            ax += v0.x + v1.x + v2.x + v3.x;
            ay += v0.y + v1.y + v2.y + v3.y;
        }
    }
    if (act)
        *reinterpret_cast<unsigned*>(&out[(size_t)wid * 80 + lane * 2]) = packbf(ax * di, ay * di);
}

// out[i] = bf16( dinv[i] * sum of pre-scaled rows ), [N,128]
__global__ __launch_bounds__(256) void gather128_k(const ushort* __restrict__ A,
        const int* __restrict__ deg, const int* __restrict__ csr,
        const float* __restrict__ dinv, ushort* __restrict__ out) {
    int wid = (blockIdx.x * blockDim.x + threadIdx.x) >> 6;
    int lane = threadIdx.x & 63;
    if (wid >= N_NODES) return;
    float di = dinv[wid];
    float2 v = bfx2(&A[(size_t)wid * 128 + lane * 2]);
    float ax = v.x, ay = v.y;
    int d = deg[wid]; if (d > PAD) d = PAD;
    const int4* e4 = reinterpret_cast<const int4*>(csr + wid * PAD);
    for (int j0 = 0; j0 < d; j0 += 4) {
        int4 e = e4[j0 >> 2];
        float2 w0 = bfx2(&A[(size_t)e.x * 128 + lane * 2]);
        float2 w1 = bfx2(&A[(size_t)e.y * 128 + lane * 2]);
        float2 w2 = bfx2(&A[(size_t)e.z * 128 + lane * 2]);
        float2 w3 = bfx2(&A[(size_t)e.w * 128 + lane * 2]);
        ax += w0.x + w1.x + w2.x + w3.x;
        ay += w0.y + w1.y + w2.y + w3.y;
    }
    *reinterpret_cast<unsigned*>(&out[(size_t)wid * 128 + lane * 2]) = packbf(ax * di, ay * di);
}

// ---------------- fused layer-3 gather + mean-pool + MLP head (8 waves/graph) ----------------

__global__ __launch_bounds__(512) void pool_head_k(
        const ushort* __restrict__ A,      // layer-3 GEMM output [N,128] bf16, pre-scaled
        const int* __restrict__ deg, const int* __restrict__ csr,
        const float* __restrict__ dinv, const float* __restrict__ b3,
        const int* __restrict__ batch,
        const float* __restrict__ fw1, const float* __restrict__ fb1,
        const float* __restrict__ fw2, const float* __restrict__ fb2,
        float* __restrict__ out) {
    __shared__ float part[8][HID];
    __shared__ float ps[HID];
    const int g = blockIdx.x;
    const int w = threadIdx.x >> 6, lane = threadIdx.x & 63;

    int start, end;
    {
        int l = 0, h = N_NODES;
        while (l < h) { int m = (l + h) >> 1; if (batch[m] < g) l = m + 1; else h = m; }
        start = l;
        h = N_NODES;
        while (l < h) { int m = (l + h) >> 1; if (batch[m] < g + 1) l = m + 1; else h = m; }
        end = l;
    }

    float sx = 0.f, sy = 0.f;
    const float bx = b3[lane * 2], by = b3[lane * 2 + 1];
    for (int i = start + w; i < end; i += 8) {
        float di = dinv[i];
        float2 v = bfx2(&A[(size_t)i * 128 + lane * 2]);
        float ax = v.x, ay = v.y;
        int d = deg[i]; if (d > PAD) d = PAD;
        const int4* e4 = reinterpret_cast<const int4*>(csr + i * PAD);
        for (int j0 = 0; j0 < d; j0 += 4) {
            int4 e = e4[j0 >> 2];
            float2 w0 = bfx2(&A[(size_t)e.x * 128 + lane * 2]);
            float2 w1 = bfx2(&A[(size_t)e.y * 128 + lane * 2]);
            float2 w2 = bfx2(&A[(size_t)e.z * 128 + lane * 2]);
            float2 w3 = bfx2(&A[(size_t)e.w * 128 + lane * 2]);
            ax += w0.x + w1.x + w2.x + w3.x;
            ay += w0.y + w1.y + w2.y + w3.y;
        }
        sx += fmaxf(ax * di + bx, 0.f);
        sy += fmaxf(ay * di + by, 0.f);
    }
    part[w][lane * 2] = sx;
    part[w][lane * 2 + 1] = sy;
    __syncthreads();

    if (w == 0) {
        float inv = (end > start) ? 1.0f / (float)(end - start) : 0.0f;
        float s0 = 0.f, s1 = 0.f;
        #pragma unroll
        for (int q = 0; q < 8; ++q) {
            s0 += part[q][lane * 2];
            s1 += part[q][lane * 2 + 1];
        }
        ps[lane * 2] = s0 * inv;
        ps[lane * 2 + 1] = s1 * inv;
    }
    __syncthreads();

    if (w == 0) {
        float acc = fb1[lane];
        #pragma unroll 8
        for (int k = 0; k < HID; ++k) acc = fmaf(ps[k], fw1[k * 64 + lane], acc);
        float v = fmaxf(acc, 0.0f) * fw2[lane];
        #pragma unroll
        for (int off = 32; off > 0; off >>= 1) v += __shfl_down(v, off);
        if (lane == 0) out[g] = v + fb2[0];
    }
}

// ---------------- launch ----------------

extern "C" void kernel_launch(void* const* d_in, const int* in_sizes, int n_in,
                              void* d_out, int out_size, void* d_ws, size_t ws_size,
                              hipStream_t stream) {
    const float* x     = (const float*)d_in[0];
    const int*   ei    = (const int*)d_in[1];
    const int*   batch = (const int*)d_in[2];
    const float* W1 = (const float*)d_in[3];
    const float* b1 = (const float*)d_in[4];
    const float* W2 = (const float*)d_in[5];
    const float* b2 = (const float*)d_in[6];
    const float* W3 = (const float*)d_in[7];
    const float* b3 = (const float*)d_in[8];
    const float* fw1 = (const float*)d_in[9];
    const float* fb1 = (const float*)d_in[10];
    const float* fw2 = (const float*)d_in[11];
    const float* fb2 = (const float*)d_in[12];
    float* out = (float*)d_out;

    const int* src = ei;
    const int* dst = ei + N_EDGES;

    // workspace layout (~120 MB)
    char* p = (char*)d_ws;
    float*  dinv  = (float*)p;  p += 100352 * 4;
    int*    cur   = (int*)p;    p += 100352 * 4;
    int*    csr   = (int*)p;    p += (size_t)N_NODES * PAD * 4;
    ushort* w1h   = (ushort*)p; p += 256 * 256 * 2;
    ushort* w2h   = (ushort*)p; p += 256 * 256 * 2;
    ushort* w3h   = (ushort*)p; p += 256 * 256 * 2;
    ushort* xb    = (ushort*)p; p += (size_t)(N_NODES + 1) * 80 * 2;
    ushort* xpadb = (ushort*)p; p += (size_t)N_NODES * 80 * 2;
    ushort* buf1  = (ushort*)p; p += (size_t)(N_NODES + 1) * 128 * 2;
    ushort* buf2  = (ushort*)p; p += (size_t)N_NODES * 128 * 2;
    ushort* buf3  = (ushort*)p; p += (size_t)(N_NODES + 1) * 128 * 2;

    const int T = 256;
    const int gw = (N_NODES * 64 + T - 1) / T;  // one wave per node

    // setup (cursor=0, csr=SENT, sentinel rows=0), CSR fill, dinv, x->bf16 pre-scaled
    setup_k<<<(N_NODES * PAD / 4 + T - 1) / T, T, 0, stream>>>(cur, (int4*)csr, xb, buf1, buf3);
    fill_csr_k<<<(N_EDGES + T - 1) / T, T, 0, stream>>>(src, dst, cur, csr);
    dinv_k<<<(N_NODES + T - 1) / T, T, 0, stream>>>(cur, dinv, N_NODES);
    x2bf_k<<<(N_NODES * 80 + T - 1) / T, T, 0, stream>>>(x, dinv, xb);

    // weight preps (single bf16 plane, transposed [N][256])
    prep_wt_k<<<(128 * 256 + T - 1) / T, T, 0, stream>>>(W1, w1h, NODE_F, 128);
    prep_wt_k<<<(256 * 256 + T - 1) / T, T, 0, stream>>>(W2, w2h, HID, 256);
    prep_wt_k<<<(128 * 256 + T - 1) / T, T, 0, stream>>>(W3, w3h, 2 * HID, 128);

    // layer 1: gather-first (pure bf16 sum), GEMM K=80 + bias + relu, pre-scaled bf16 out
    gather78_k<<<gw, T, 0, stream>>>(xb, cur, csr, dinv, xpadb);
    gemm1_k<<<782, 256, 0, stream>>>(xpadb, N_NODES, w1h, b1, dinv, buf1);

    // layer 2 gather (bf16), then fused L2+L3 GEMM (1-term, BM=128, 8 waves), pre-scaled bf16 out
    gather128_k<<<gw, T, 0, stream>>>(buf1, cur, csr, dinv, buf2);
    gemm23_k<<<782, 512, 0, stream>>>(buf2, w2h, b2, w3h, dinv, buf3, N_NODES);

    // layer-3 gather + bias + relu + mean-pool + MLP head
    pool_head_k<<<N_GRAPHS, 512, 0, stream>>>(buf3, cur, csr, dinv, b3, batch,
                                              fw1, fb1, fw2, fb2, out);
}

// Round 11
// 308.946 us; speedup vs baseline: 4.5341x; 1.0585x over previous
//
#include <hip/hip_runtime.h>

#define N_NODES 100000
#define N_EDGES 400000
#define N_GRAPHS 2000
#define NODE_F 78
#define HID 128
#define PAD 32
#define SENT N_NODES   // sentinel row index (zeroed row appended to gathered buffers)

typedef __attribute__((ext_vector_type(8))) short short8v;
typedef __attribute__((ext_vector_type(4))) float f32x4;

__device__ __forceinline__ ushort f2bf(float f) {
    unsigned u = __float_as_uint(f);
    unsigned r = (u + 0x7FFFu + ((u >> 16) & 1u)) >> 16;  // round-to-nearest-even
    return (ushort)r;
}
__device__ __forceinline__ float bf2f(ushort b) {
    return __uint_as_float(((unsigned)b) << 16);
}
__device__ __forceinline__ float2 bfx2(const ushort* p) {
    unsigned u = *reinterpret_cast<const unsigned*>(p);
    return make_float2(__uint_as_float(u << 16), __uint_as_float(u & 0xffff0000u));
}
__device__ __forceinline__ unsigned packbf(float a, float b) {
    return (unsigned)f2bf(a) | ((unsigned)f2bf(b) << 16);
}
// async global->LDS, 16B per lane; lds base wave-uniform, gsrc per-lane
__device__ __forceinline__ void gload16(const ushort* g, ushort* l) {
    __builtin_amdgcn_global_load_lds((const __attribute__((address_space(1))) unsigned int*)g,
                                     (__attribute__((address_space(3))) unsigned int*)l, 16, 0, 0);
}

// ---------------- setup: zero cursor, sentinel-fill csr, zero sentinel rows ----------------

__global__ void setup_k(int* __restrict__ cursor, int4* __restrict__ csr4,
                        ushort* __restrict__ xb, ushort* __restrict__ b1,
                        ushort* __restrict__ b3) {
    int i = blockIdx.x * blockDim.x + threadIdx.x;
    if (i < N_NODES * PAD / 4) csr4[i] = make_int4(SENT, SENT, SENT, SENT);
    if (i < N_NODES) cursor[i] = 0;
    if (i < 80) xb[(size_t)N_NODES * 80 + i] = 0;
    if (i < 128) {
        b1[(size_t)N_NODES * 128 + i] = 0;
        b3[(size_t)N_NODES * 128 + i] = 0;
    }
}

__global__ void fill_csr_k(const int* __restrict__ src, const int* __restrict__ dst,
                           int* __restrict__ cursor, int* __restrict__ csr) {
    int e = blockIdx.x * blockDim.x + threadIdx.x;
    if (e >= N_EDGES) return;
    int s = src[e], d = dst[e];
    int p = atomicAdd(&cursor[d], 1);
    if (p < PAD) csr[d * PAD + p] = s;
}

__global__ void dinv_k(const int* __restrict__ deg, float* __restrict__ dinv, int n) {
    int i = blockIdx.x * blockDim.x + threadIdx.x;
    if (i < n) dinv[i] = rsqrtf((float)deg[i] + 1.0f);
}

// ---------------- x -> bf16 pre-scaled by dinv[row], padded to 80 cols ----------------

__global__ void x2bf_k(const float* __restrict__ x, const float* __restrict__ dinv,
                       ushort* __restrict__ xb) {
    int idx = blockIdx.x * blockDim.x + threadIdx.x;
    if (idx >= N_NODES * 80) return;
    int n = idx / 80, f = idx - n * 80;
    xb[idx] = (f < NODE_F) ? f2bf(x[(long long)n * NODE_F + f] * dinv[n]) : (ushort)0;
}

// ---------------- weight preps ----------------

// W1: [K][128] fp32 -> bf16 [n][256] zero-padded (old layout, used by gemm1)
__global__ void prep_wt_k(const float* __restrict__ W, ushort* __restrict__ Wth,
                          int K, int N) {
    int idx = blockIdx.x * blockDim.x + threadIdx.x;
    if (idx >= N * 256) return;
    int n = idx >> 8, k = idx & 255;
    Wth[idx] = (k < K) ? f2bf(W[(long long)k * N + n]) : (ushort)0;
}

// W2 [128k][256n] -> LDS image: 4 quarter-tiles (64n x 128k, 16KB), XOR-swizzled rows
__global__ void prep_w2img_k(const float* __restrict__ W2, ushort* __restrict__ img) {
    int idx = blockIdx.x * blockDim.x + threadIdx.x;
    if (idx >= 256 * 128) return;
    int n = idx >> 7, k = idx & 127;
    int c = k >> 3;                                  // chunk 0..15
    int slot = (c & 8) | ((c & 7) ^ (n & 7));
    img[n * 128 + slot * 8 + (k & 7)] = f2bf(W2[(long long)k * 256 + n]);
}

// W3 [256k][128n] -> LDS image: 4 k-chunk tiles (128n x 64k, 16KB), XOR-swizzled rows
__global__ void prep_w3img_k(const float* __restrict__ W3, ushort* __restrict__ img) {
    int idx = blockIdx.x * blockDim.x + threadIdx.x;
    if (idx >= 128 * 256) return;
    int n = idx >> 8, k = idx & 255;
    int ch = k >> 6, cc = (k >> 3) & 7;
    img[ch * 8192 + n * 64 + ((cc ^ (n & 7)) * 8) + (k & 7)] = f2bf(W3[(long long)k * 128 + n]);
}

// ---------------- layer-1 GEMM: C_bf16 = relu(A_bf16[M,80] @ W1 + b1) * dinv[row] ----------------

__global__ __launch_bounds__(256) void gemm1_k(
        const ushort* __restrict__ A, int M,
        const ushort* __restrict__ Wth, const float* __restrict__ bias,
        const float* __restrict__ dinv, ushort* __restrict__ C) {
    __shared__ ushort At[128 * 64];
    __shared__ ushort Bh[128 * 64];
    const int tid = threadIdx.x;
    const int w = tid >> 6, l = tid & 63;
    const int bm = blockIdx.x * 128;

    f32x4 acc[2][8];
    #pragma unroll
    for (int m = 0; m < 2; ++m)
        #pragma unroll
        for (int j = 0; j < 8; ++j)
            acc[m][j] = (f32x4){0.f, 0.f, 0.f, 0.f};

    for (int k0 = 0; k0 < 128; k0 += 64) {
        __syncthreads();
        #pragma unroll
        for (int i = 0; i < 4; ++i) {
            int idx = tid + i * 256;
            int r = idx >> 3, s0 = idx & 7;
            int gr = bm + r; if (gr >= M) gr = M - 1;
            int kk = k0 + s0 * 8;
            short8v v;
            if (kk < 80) v = *reinterpret_cast<const short8v*>(&A[(size_t)gr * 80 + kk]);
            else v = (short8v){0,0,0,0,0,0,0,0};
            *reinterpret_cast<short8v*>(&At[r * 64 + (s0 ^ (r & 7)) * 8]) = v;
        }
        #pragma unroll
        for (int i = 0; i < 4; ++i) {
            int idx = tid + i * 256;
            int n = idx >> 3, s0 = idx & 7;
            long long g = (long long)n * 256 + k0 + s0 * 8;
            *reinterpret_cast<short8v*>(&Bh[n * 64 + (s0 ^ (n & 7)) * 8]) =
                *reinterpret_cast<const short8v*>(&Wth[g]);
        }
        __syncthreads();
        #pragma unroll
        for (int ks = 0; ks < 2; ++ks) {
            short8v ah[2];
            #pragma unroll
            for (int m = 0; m < 2; ++m) {
                int r = w * 32 + m * 16 + (l & 15);
                ah[m] = *reinterpret_cast<const short8v*>(
                    &At[r * 64 + ((ks * 4 + (l >> 4)) ^ (r & 7)) * 8]);
            }
            #pragma unroll
            for (int j = 0; j < 8; ++j) {
                int n = j * 16 + (l & 15);
                short8v bh = *reinterpret_cast<const short8v*>(
                    &Bh[n * 64 + ((ks * 4 + (l >> 4)) ^ (n & 7)) * 8]);
                #pragma unroll
                for (int m = 0; m < 2; ++m)
                    acc[m][j] = __builtin_amdgcn_mfma_f32_16x16x32_bf16(ah[m], bh, acc[m][j], 0, 0, 0);
            }
        }
    }

    float dv[2][4];
    #pragma unroll
    for (int m = 0; m < 2; ++m)
        #pragma unroll
        for (int rg = 0; rg < 4; ++rg) {
            int gr = bm + w * 32 + m * 16 + (l >> 4) * 4 + rg;
            dv[m][rg] = (gr < M) ? dinv[gr] : 0.f;
        }
    #pragma unroll
    for (int j = 0; j < 8; ++j) {
        int gc = j * 16 + (l & 15);
        float bv = bias[gc];
        #pragma unroll
        for (int m = 0; m < 2; ++m) {
            #pragma unroll
            for (int rg = 0; rg < 4; ++rg) {
                int gr = bm + w * 32 + m * 16 + (l >> 4) * 4 + rg;
                if (gr < M)
                    C[(size_t)gr * 128 + gc] = f2bf(fmaxf(acc[m][j][rg] + bv, 0.0f) * dv[m][rg]);
            }
        }
    }
}

// ---------------- fused layer2+layer3 GEMM v3: DMA staging + dbuf weights + per-wave T ----------------
// BM=128, 512 threads = 8 waves, wave w owns rows w*16..+15.
// A [128x128] staged ONCE via global_load_lds (pre-swizzled rows in buf2).
// W2/W3 16KB tiles double-buffered; next tile issued before MFMA cluster. 9 barriers total.

__global__ __launch_bounds__(512) void gemm23_k(
        const ushort* __restrict__ A,    // [M,128] bf16 rows, pre-swizzled 16B chunks
        const ushort* __restrict__ W2i, const float* __restrict__ b2,
        const ushort* __restrict__ W3i, const float* __restrict__ dinv,
        ushort* __restrict__ C, int M) {
    __shared__ ushort At[128 * 128];     // 32KB
    __shared__ ushort Wb[2][8192];       // 2x16KB
    __shared__ ushort Tb[8][1024];       // 8x2KB, per-wave
    const int tid = threadIdx.x;
    const int w = tid >> 6, l = tid & 63;
    const int bm = blockIdx.x * 128;

    // prologue: A tile (32 x 1KB wave-chunks) + W2 quarter 0 (16 x 1KB)
    {
        const ushort* asrc = A + (size_t)bm * 128;
        #pragma unroll
        for (int i = 0; i < 4; ++i) {
            int chunk = w * 4 + i;
            gload16(asrc + chunk * 512 + l * 8, &At[chunk * 512]);
        }
        #pragma unroll
        for (int i = 0; i < 2; ++i) {
            int chunk = w * 2 + i;
            gload16(W2i + chunk * 512 + l * 8, &Wb[0][chunk * 512]);
        }
    }
    __syncthreads();

    f32x4 acc2[16];
    #pragma unroll
    for (int j = 0; j < 16; ++j) acc2[j] = (f32x4){0.f, 0.f, 0.f, 0.f};

    // ---- phase 1: T = A @ W2, by n-quarters (64 cols each, full K=128) ----
    #pragma unroll
    for (int q = 0; q < 4; ++q) {
        // issue next tile: W2 quarter q+1, or W3 chunk 0 after last quarter
        const ushort* nsrc = (q < 3) ? (W2i + (q + 1) * 8192) : W3i;
        #pragma unroll
        for (int i = 0; i < 2; ++i) {
            int chunk = w * 2 + i;
            gload16(nsrc + chunk * 512 + l * 8, &Wb[(q + 1) & 1][chunk * 512]);
        }
        const ushort* wb = Wb[q & 1];
        #pragma unroll
        for (int ks = 0; ks < 4; ++ks) {
            int r = w * 16 + (l & 15);
            int ck = ks * 4 + (l >> 4);
            int sa = (ck & 8) | ((ck & 7) ^ (r & 7));
            short8v ah = *reinterpret_cast<const short8v*>(&At[r * 128 + sa * 8]);
            #pragma unroll
            for (int jt = 0; jt < 4; ++jt) {
                int n = jt * 16 + (l & 15);
                int sb = (ck & 8) | ((ck & 7) ^ (n & 7));
                short8v bh = *reinterpret_cast<const short8v*>(&wb[n * 128 + sb * 8]);
                acc2[q * 4 + jt] = __builtin_amdgcn_mfma_f32_16x16x32_bf16(ah, bh, acc2[q * 4 + jt], 0, 0, 0);
            }
        }
        __syncthreads();
    }

    // ---- phase 2: C3 = relu(T+b2) @ W3, by k-chunks of 64; T exchange is intra-wave ----
    f32x4 acc3[8];
    #pragma unroll
    for (int j = 0; j < 8; ++j) acc3[j] = (f32x4){0.f, 0.f, 0.f, 0.f};

    #pragma unroll
    for (int ch = 0; ch < 4; ++ch) {
        if (ch < 3) {
            const ushort* nsrc = W3i + (ch + 1) * 8192;
            #pragma unroll
            for (int i = 0; i < 2; ++i) {
                int chunk = w * 2 + i;
                gload16(nsrc + chunk * 512 + l * 8, &Wb[(ch + 1) & 1][chunk * 512]);
            }
        }
        // write T chunk (16 rows x 64 cols) into own wave buffer
        #pragma unroll
        for (int jj = 0; jj < 4; ++jj) {
            int j = ch * 4 + jj;
            float bv = b2[ch * 64 + jj * 16 + (l & 15)];
            #pragma unroll
            for (int rg = 0; rg < 4; ++rg) {
                int rr = (l >> 4) * 4 + rg;
                int cl = jj * 16 + (l & 15);
                Tb[w][rr * 64 + (((cl >> 3) ^ (rr & 7)) * 8) + (cl & 7)] =
                    f2bf(fmaxf(acc2[j][rg] + bv, 0.f));
            }
        }
        const ushort* wb = Wb[ch & 1];
        #pragma unroll
        for (int ks = 0; ks < 2; ++ks) {
            int rt = l & 15;
            int ck = ks * 4 + (l >> 4);
            short8v ah = *reinterpret_cast<const short8v*>(&Tb[w][rt * 64 + ((ck ^ (rt & 7)) * 8)]);
            #pragma unroll
            for (int j3 = 0; j3 < 8; ++j3) {
                int n = j3 * 16 + (l & 15);
                short8v bh = *reinterpret_cast<const short8v*>(&wb[n * 64 + ((ck ^ (n & 7)) * 8)]);
                acc3[j3] = __builtin_amdgcn_mfma_f32_16x16x32_bf16(ah, bh, acc3[j3], 0, 0, 0);
            }
        }
        __syncthreads();
    }

    // epilogue: pre-scale by dinv[row] -> bf16 (normal row layout)
    float dv[4];
    #pragma unroll
    for (int rg = 0; rg < 4; ++rg) {
        int gr = bm + w * 16 + (l >> 4) * 4 + rg;
        dv[rg] = (gr < M) ? dinv[gr] : 0.f;
    }
    #pragma unroll
    for (int j = 0; j < 8; ++j) {
        int gc = j * 16 + (l & 15);
        #pragma unroll
        for (int rg = 0; rg < 4; ++rg) {
            int gr = bm + w * 16 + (l >> 4) * 4 + rg;
            if (gr < M) C[(size_t)gr * 128 + gc] = f2bf(acc3[j][rg] * dv[rg]);
        }
    }
}

// ---------------- gathers: pure row sums, bf16 in AND out ----------------

// out[i] = bf16( dinv[i] * sum rows ), [N,80] (normal layout, feeds gemm1)
__global__ __launch_bounds__(256) void gather78_k(const ushort* __restrict__ Xb,
        const int* __restrict__ deg, const int* __restrict__ csr,
        const float* __restrict__ dinv, ushort* __restrict__ out) {
    int wid = (blockIdx.x * blockDim.x + threadIdx.x) >> 6;
    int lane = threadIdx.x & 63;
    if (wid >= N_NODES) return;
    float di = dinv[wid];
    float ax = 0.f, ay = 0.f;
    bool act = lane < 40;
    if (act) {
        float2 v = bfx2(&Xb[(size_t)wid * 80 + lane * 2]);
        ax = v.x; ay = v.y;
    }
    int d = deg[wid]; if (d > PAD) d = PAD;
    const int4* e4 = reinterpret_cast<const int4*>(csr + wid * PAD);
    for (int j0 = 0; j0 < d; j0 += 4) {
        int4 e = e4[j0 >> 2];
        if (act) {
            float2 v0 = bfx2(&Xb[(size_t)e.x * 80 + lane * 2]);
            float2 v1 = bfx2(&Xb[(size_t)e.y * 80 + lane * 2]);
            float2 v2 = bfx2(&Xb[(size_t)e.z * 80 + lane * 2]);
            float2 v3 = bfx2(&Xb[(size_t)e.w * 80 + lane * 2]);
            ax += v0.x + v1.x + v2.x + v3.x;
            ay += v0.y + v1.y + v2.y + v3.y;
        }
    }
    if (act)
        *reinterpret_cast<unsigned*>(&out[(size_t)wid * 80 + lane * 2]) = packbf(ax * di, ay * di);
}

// out[i] = bf16( dinv[i] * sum rows ), [N,128], rows PRE-SWIZZLED for gemm23 DMA staging
__global__ __launch_bounds__(256) void gather128_k(const ushort* __restrict__ A,
        const int* __restrict__ deg, const int* __restrict__ csr,
        const float* __restrict__ dinv, ushort* __restrict__ out) {
    int wid = (blockIdx.x * blockDim.x + threadIdx.x) >> 6;
    int lane = threadIdx.x & 63;
    if (wid >= N_NODES) return;
    float di = dinv[wid];
    float2 v = bfx2(&A[(size_t)wid * 128 + lane * 2]);
    float ax = v.x, ay = v.y;
    int d = deg[wid]; if (d > PAD) d = PAD;
    const int4* e4 = reinterpret_cast<const int4*>(csr + wid * PAD);
    for (int j0 = 0; j0 < d; j0 += 4) {
        int4 e = e4[j0 >> 2];
        float2 w0 = bfx2(&A[(size_t)e.x * 128 + lane * 2]);
        float2 w1 = bfx2(&A[(size_t)e.y * 128 + lane * 2]);
        float2 w2 = bfx2(&A[(size_t)e.z * 128 + lane * 2]);
        float2 w3 = bfx2(&A[(size_t)e.w * 128 + lane * 2]);
        ax += w0.x + w1.x + w2.x + w3.x;
        ay += w0.y + w1.y + w2.y + w3.y;
    }
    // swizzled write: 4B unit u=lane -> chunk c=u>>2, kt=c>>3, cc=c&7, slot=kt*8+(cc^(row&7))
    int kt = lane >> 5, cc = (lane >> 2) & 7, q4 = lane & 3;
    int slot = kt * 8 + (cc ^ (wid & 7));
    *reinterpret_cast<unsigned*>(&out[(size_t)wid * 128 + slot * 8 + q4 * 2]) = packbf(ax * di, ay * di);
}

// ---------------- fused layer-3 gather + mean-pool + MLP head (8 waves/graph) ----------------

__global__ __launch_bounds__(512) void pool_head_k(
        const ushort* __restrict__ A,      // [N,128] bf16, pre-scaled, normal layout
        const int* __restrict__ deg, const int* __restrict__ csr,
        const float* __restrict__ dinv, const float* __restrict__ b3,
        const int* __restrict__ batch,
        const float* __restrict__ fw1, const float* __restrict__ fb1,
        const float* __restrict__ fw2, const float* __restrict__ fb2,
        float* __restrict__ out) {
    __shared__ float part[8][HID];
    __shared__ float ps[HID];
    const int g = blockIdx.x;
    const int w = threadIdx.x >> 6, lane = threadIdx.x & 63;

    int start, end;
    {
        int l = 0, h = N_NODES;
        while (l < h) { int m = (l + h) >> 1; if (batch[m] < g) l = m + 1; else h = m; }
        start = l;
        h = N_NODES;
        while (l < h) { int m = (l + h) >> 1; if (batch[m] < g + 1) l = m + 1; else h = m; }
        end = l;
    }

    float sx = 0.f, sy = 0.f;
    const float bx = b3[lane * 2], by = b3[lane * 2 + 1];
    for (int i = start + w; i < end; i += 8) {
        float di = dinv[i];
        float2 v = bfx2(&A[(size_t)i * 128 + lane * 2]);
        float ax = v.x, ay = v.y;
        int d = deg[i]; if (d > PAD) d = PAD;
        const int4* e4 = reinterpret_cast<const int4*>(csr + i * PAD);
        for (int j0 = 0; j0 < d; j0 += 4) {
            int4 e = e4[j0 >> 2];
            float2 w0 = bfx2(&A[(size_t)e.x * 128 + lane * 2]);
            float2 w1 = bfx2(&A[(size_t)e.y * 128 + lane * 2]);
            float2 w2 = bfx2(&A[(size_t)e.z * 128 + lane * 2]);
            float2 w3 = bfx2(&A[(size_t)e.w * 128 + lane * 2]);
            ax += w0.x + w1.x + w2.x + w3.x;
            ay += w0.y + w1.y + w2.y + w3.y;
        }
        sx += fmaxf(ax * di + bx, 0.f);
        sy += fmaxf(ay * di + by, 0.f);
    }
    part[w][lane * 2] = sx;
    part[w][lane * 2 + 1] = sy;
    __syncthreads();

    if (w == 0) {
        float inv = (end > start) ? 1.0f / (float)(end - start) : 0.0f;
        float s0 = 0.f, s1 = 0.f;
        #pragma unroll
        for (int q = 0; q < 8; ++q) {
            s0 += part[q][lane * 2];
            s1 += part[q][lane * 2 + 1];
        }
        ps[lane * 2] = s0 * inv;
        ps[lane * 2 + 1] = s1 * inv;
    }
    __syncthreads();

    if (w == 0) {
        float acc = fb1[lane];
        #pragma unroll 8
        for (int k = 0; k < HID; ++k) acc = fmaf(ps[k], fw1[k * 64 + lane], acc);
        float v = fmaxf(acc, 0.0f) * fw2[lane];
        #pragma unroll
        for (int off = 32; off > 0; off >>= 1) v += __shfl_down(v, off);
        if (lane == 0) out[g] = v + fb2[0];
    }
}

// ---------------- launch ----------------

extern "C" void kernel_launch(void* const* d_in, const int* in_sizes, int n_in,
                              void* d_out, int out_size, void* d_ws, size_t ws_size,
                              hipStream_t stream) {
    const float* x     = (const float*)d_in[0];
    const int*   ei    = (const int*)d_in[1];
    const int*   batch = (const int*)d_in[2];
    const float* W1 = (const float*)d_in[3];
    const float* b1 = (const float*)d_in[4];
    const float* W2 = (const float*)d_in[5];
    const float* b2 = (const float*)d_in[6];
    const float* W3 = (const float*)d_in[7];
    const float* b3 = (const float*)d_in[8];
    const float* fw1 = (const float*)d_in[9];
    const float* fb1 = (const float*)d_in[10];
    const float* fw2 = (const float*)d_in[11];
    const float* fb2 = (const float*)d_in[12];
    float* out = (float*)d_out;

    const int* src = ei;
    const int* dst = ei + N_EDGES;

    // workspace layout (~120 MB)
    char* p = (char*)d_ws;
    float*  dinv  = (float*)p;  p += 100352 * 4;
    int*    cur   = (int*)p;    p += 100352 * 4;
    int*    csr   = (int*)p;    p += (size_t)N_NODES * PAD * 4;
    ushort* w1h   = (ushort*)p; p += 256 * 256 * 2;
    ushort* img2  = (ushort*)p; p += 256 * 128 * 2;   // W2 LDS image (64KB)
    ushort* img3  = (ushort*)p; p += 128 * 256 * 2;   // W3 LDS image (64KB)
    ushort* xb    = (ushort*)p; p += (size_t)(N_NODES + 1) * 80 * 2;
    ushort* xpadb = (ushort*)p; p += (size_t)N_NODES * 80 * 2;
    ushort* buf1  = (ushort*)p; p += (size_t)(N_NODES + 1) * 128 * 2;
    ushort* buf2  = (ushort*)p; p += (size_t)N_NODES * 128 * 2;   // pre-swizzled rows
    ushort* buf3  = (ushort*)p; p += (size_t)(N_NODES + 1) * 128 * 2;

    const int T = 256;
    const int gw = (N_NODES * 64 + T - 1) / T;  // one wave per node

    // setup, CSR fill, dinv, x->bf16 pre-scaled
    setup_k<<<(N_NODES * PAD / 4 + T - 1) / T, T, 0, stream>>>(cur, (int4*)csr, xb, buf1, buf3);
    fill_csr_k<<<(N_EDGES + T - 1) / T, T, 0, stream>>>(src, dst, cur, csr);
    dinv_k<<<(N_NODES + T - 1) / T, T, 0, stream>>>(cur, dinv, N_NODES);
    x2bf_k<<<(N_NODES * 80 + T - 1) / T, T, 0, stream>>>(x, dinv, xb);

    // weight preps
    prep_wt_k<<<(128 * 256 + T - 1) / T, T, 0, stream>>>(W1, w1h, NODE_F, 128);
    prep_w2img_k<<<(256 * 128 + T - 1) / T, T, 0, stream>>>(W2, img2);
    prep_w3img_k<<<(128 * 256 + T - 1) / T, T, 0, stream>>>(W3, img3);

    // layer 1
    gather78_k<<<gw, T, 0, stream>>>(xb, cur, csr, dinv, xpadb);
    gemm1_k<<<782, 256, 0, stream>>>(xpadb, N_NODES, w1h, b1, dinv, buf1);

    // layer 2 gather (swizzled write), fused L2+L3 GEMM v3
    gather128_k<<<gw, T, 0, stream>>>(buf1, cur, csr, dinv, buf2);
    gemm23_k<<<782, 512, 0, stream>>>(buf2, img2, b2, img3, dinv, buf3, N_NODES);

    // layer-3 gather + mean-pool + MLP head
    pool_head_k<<<N_GRAPHS, 512, 0, stream>>>(buf3, cur, csr, dinv, b3, batch,
                                              fw1, fb1, fw2, fb2, out);
}